// Round 1
// baseline (835.395 us; speedup 1.0000x reference)
//
#include <hip/hip_runtime.h>
#include <hip/hip_bf16.h>

#define IN_DIM  512
#define HID_DIM 256
#define OUT_DIM 64
#define KITERS  5

// ---------------- CSR build ----------------

__global__ void hist_kernel(const int* __restrict__ ei, int* __restrict__ deg, int E) {
    int e = blockIdx.x * 256 + threadIdx.x;
    if (e < E) atomicAdd(&deg[ei[E + e]], 1);
}

__global__ __launch_bounds__(1024) void scan_kernel(const int* __restrict__ deg,
                                                    int* __restrict__ offs,
                                                    float* __restrict__ dinv, int N) {
    __shared__ int sums[1024];
    int tid = threadIdx.x;
    int chunk = (N + 1023) / 1024;
    int start = tid * chunk;
    int end   = min(start + chunk, N);
    int s = 0;
    for (int i = start; i < end; ++i) s += deg[i];
    sums[tid] = s;
    __syncthreads();
    for (int off = 1; off < 1024; off <<= 1) {
        int v = 0;
        if (tid >= off) v = sums[tid - off];
        __syncthreads();
        sums[tid] += v;
        __syncthreads();
    }
    int run = sums[tid] - s;   // exclusive prefix
    for (int i = start; i < end; ++i) {
        offs[i] = run;
        run += deg[i];
        dinv[i] = rsqrtf((float)(deg[i] + 1));  // +1 self-loop
    }
    if (tid == 1023) offs[N] = sums[1023];
}

__global__ void fill_kernel(const int* __restrict__ ei, const int* __restrict__ offs,
                            int* __restrict__ cursor, int* __restrict__ csrc, int E) {
    int e = blockIdx.x * 256 + threadIdx.x;
    if (e < E) {
        int s = ei[e];
        int d = ei[E + e];
        int pos = offs[d] + atomicAdd(&cursor[d], 1);
        csrc[pos] = s;
    }
}

// ---------------- GEMM: C[M,N] = act(A[M,K] @ B[N,K]^T + bias) ----------------

template<int BM, int BN, int BK, int TM, int TN, bool RELU>
__global__ __launch_bounds__(256) void gemm_bt(const float* __restrict__ A,
                                               const float* __restrict__ B,
                                               const float* __restrict__ bias,
                                               float* __restrict__ C,
                                               int M, int N, int K) {
    __shared__ float As[BK][BM + 4];
    __shared__ float Bs[BK][BN + 4];
    constexpr int TCOLS = BN / TN;
    const int tid = threadIdx.x;
    const int tn = tid % TCOLS;
    const int tm = tid / TCOLS;
    const int m0 = blockIdx.x * BM;
    const int n0 = blockIdx.y * BN;

    float acc[TM][TN];
#pragma unroll
    for (int i = 0; i < TM; ++i)
#pragma unroll
        for (int j = 0; j < TN; ++j) acc[i][j] = 0.0f;

    constexpr int A_QUADS = BM * BK / 4;
    constexpr int B_QUADS = BN * BK / 4;
    constexpr int KQ = BK / 4;

    for (int k0 = 0; k0 < K; k0 += BK) {
        __syncthreads();
#pragma unroll
        for (int q = tid; q < A_QUADS; q += 256) {
            int row = q / KQ;
            int kq  = (q % KQ) * 4;
            float4 v = make_float4(0.f, 0.f, 0.f, 0.f);
            if (m0 + row < M)
                v = *reinterpret_cast<const float4*>(&A[(size_t)(m0 + row) * K + k0 + kq]);
            As[kq + 0][row] = v.x;
            As[kq + 1][row] = v.y;
            As[kq + 2][row] = v.z;
            As[kq + 3][row] = v.w;
        }
#pragma unroll
        for (int q = tid; q < B_QUADS; q += 256) {
            int row = q / KQ;
            int kq  = (q % KQ) * 4;
            float4 v = *reinterpret_cast<const float4*>(&B[(size_t)(n0 + row) * K + k0 + kq]);
            Bs[kq + 0][row] = v.x;
            Bs[kq + 1][row] = v.y;
            Bs[kq + 2][row] = v.z;
            Bs[kq + 3][row] = v.w;
        }
        __syncthreads();
#pragma unroll
        for (int k = 0; k < BK; ++k) {
            float a[TM], b[TN];
#pragma unroll
            for (int i = 0; i < TM; i += 4) {
                float4 v = *reinterpret_cast<const float4*>(&As[k][tm * TM + i]);
                a[i + 0] = v.x; a[i + 1] = v.y; a[i + 2] = v.z; a[i + 3] = v.w;
            }
#pragma unroll
            for (int j = 0; j < TN; j += 4) {
                float4 v = *reinterpret_cast<const float4*>(&Bs[k][tn * TN + j]);
                b[j + 0] = v.x; b[j + 1] = v.y; b[j + 2] = v.z; b[j + 3] = v.w;
            }
#pragma unroll
            for (int i = 0; i < TM; ++i)
#pragma unroll
                for (int j = 0; j < TN; ++j)
                    acc[i][j] = fmaf(a[i], b[j], acc[i][j]);
        }
    }

    // epilogue
#pragma unroll
    for (int i = 0; i < TM; ++i) {
        int m = m0 + tm * TM + i;
        if (m >= M) continue;
#pragma unroll
        for (int j = 0; j < TN; j += 4) {
            int n = n0 + tn * TN + j;
            float4 v;
            v.x = acc[i][j + 0] + bias[n + 0];
            v.y = acc[i][j + 1] + bias[n + 1];
            v.z = acc[i][j + 2] + bias[n + 2];
            v.w = acc[i][j + 3] + bias[n + 3];
            if (RELU) {
                v.x = fmaxf(v.x, 0.f); v.y = fmaxf(v.y, 0.f);
                v.z = fmaxf(v.z, 0.f); v.w = fmaxf(v.w, 0.f);
            }
            *reinterpret_cast<float4*>(&C[(size_t)m * N + n]) = v;
        }
    }
}

// ---------------- propagation: xout = 0.9 * (A_hat @ xin) + 0.1 * h ----------------

__global__ __launch_bounds__(256) void prop_kernel(const float* __restrict__ xin,
                                                   const float* __restrict__ h,
                                                   const float* __restrict__ dinv,
                                                   const int* __restrict__ offs,
                                                   const int* __restrict__ csrc,
                                                   float* __restrict__ xout, int N) {
    int node = blockIdx.x * 4 + (threadIdx.x >> 6);
    int lane = threadIdx.x & 63;
    if (node >= N) return;
    float di = dinv[node];
    float acc = di * di * xin[(size_t)node * 64 + lane];
    int e0 = offs[node], e1 = offs[node + 1];
    for (int e = e0; e < e1; ++e) {
        int s = csrc[e];
        float w = di * dinv[s];
        acc = fmaf(w, xin[(size_t)s * 64 + lane], acc);
    }
    xout[(size_t)node * 64 + lane] = 0.9f * acc + 0.1f * h[(size_t)node * 64 + lane];
}

// ---------------- log-softmax over 64 features (wave per node) ----------------

__global__ __launch_bounds__(256) void lsm_kernel(const float* __restrict__ xin,
                                                  float* __restrict__ out, int N) {
    int node = blockIdx.x * 4 + (threadIdx.x >> 6);
    int lane = threadIdx.x & 63;
    if (node >= N) return;
    float v = xin[(size_t)node * 64 + lane];
    float m = v;
    for (int o = 32; o > 0; o >>= 1) m = fmaxf(m, __shfl_xor(m, o));
    float ex = __expf(v - m);
    float sum = ex;
    for (int o = 32; o > 0; o >>= 1) sum += __shfl_xor(sum, o);
    out[(size_t)node * 64 + lane] = v - m - __logf(sum);
}

// ---------------- launch ----------------

static inline size_t align256(size_t x) { return (x + 255) & ~(size_t)255; }

extern "C" void kernel_launch(void* const* d_in, const int* in_sizes, int n_in,
                              void* d_out, int out_size, void* d_ws, size_t ws_size,
                              hipStream_t stream) {
    const float* x  = (const float*)d_in[0];
    const float* W1 = (const float*)d_in[1];
    const float* b1 = (const float*)d_in[2];
    const float* W2 = (const float*)d_in[3];
    const float* b2 = (const float*)d_in[4];
    const int*   ei = (const int*)d_in[5];

    const int N = in_sizes[0] / IN_DIM;
    const int E = in_sizes[5] / 2;

    char* base = (char*)d_ws;
    size_t off = 0;
    float* h1   = (float*)(base + off); off += align256((size_t)N * HID_DIM * 4);
    float* h    = (float*)(base + off); off += align256((size_t)N * OUT_DIM * 4);
    float* dinv = (float*)(base + off); off += align256((size_t)N * 4);
    int*   deg  = (int*)(base + off);   off += align256((size_t)N * 4);
    int*   offs = (int*)(base + off);   off += align256((size_t)(N + 1) * 4);
    int*   cur  = (int*)(base + off);   off += align256((size_t)N * 4);
    int*   csrc = (int*)(base + off);   off += align256((size_t)E * 4);
    float* xa   = h1;                    // reuse h1 region after MLP done
    float* xo   = (float*)d_out;

    // ---- CSR build ----
    hipMemsetAsync(deg, 0, (size_t)N * 4, stream);
    hipMemsetAsync(cur, 0, (size_t)N * 4, stream);
    hist_kernel<<<(E + 255) / 256, 256, 0, stream>>>(ei, deg, E);
    scan_kernel<<<1, 1024, 0, stream>>>(deg, offs, dinv, N);
    fill_kernel<<<(E + 255) / 256, 256, 0, stream>>>(ei, offs, cur, csrc, E);

    // ---- MLP ----
    {
        dim3 g((N + 127) / 128, HID_DIM / 128);
        gemm_bt<128, 128, 16, 8, 8, true><<<g, 256, 0, stream>>>(x, W1, b1, h1, N, HID_DIM, IN_DIM);
    }
    {
        dim3 g((N + 63) / 64, OUT_DIM / 64);
        gemm_bt<64, 64, 32, 4, 4, false><<<g, 256, 0, stream>>>(h1, W2, b2, h, N, OUT_DIM, HID_DIM);
    }

    // ---- K propagation steps (ping-pong: xa <-> d_out) ----
    int blocks = (N + 3) / 4;
    prop_kernel<<<blocks, 256, 0, stream>>>(h,  h, dinv, offs, csrc, xa, N);  // iter 1
    prop_kernel<<<blocks, 256, 0, stream>>>(xa, h, dinv, offs, csrc, xo, N);  // iter 2
    prop_kernel<<<blocks, 256, 0, stream>>>(xo, h, dinv, offs, csrc, xa, N);  // iter 3
    prop_kernel<<<blocks, 256, 0, stream>>>(xa, h, dinv, offs, csrc, xo, N);  // iter 4
    prop_kernel<<<blocks, 256, 0, stream>>>(xo, h, dinv, offs, csrc, xa, N);  // iter 5

    // ---- log-softmax ----
    lsm_kernel<<<blocks, 256, 0, stream>>>(xa, xo, N);
}

// Round 2
// 694.698 us; speedup vs baseline: 1.2025x; 1.2025x over previous
//
#include <hip/hip_runtime.h>
#include <hip/hip_bf16.h>

#define IN_DIM  512
#define HID_DIM 256
#define OUT_DIM 64
#define KITERS  5

typedef __attribute__((ext_vector_type(8))) short bf16x8;
typedef __attribute__((ext_vector_type(4))) float f32x4;

static __device__ __forceinline__ ushort f2b(float f) {
    __hip_bfloat16 b = __float2bfloat16(f);
    return *reinterpret_cast<ushort*>(&b);
}

// ---------------- CSR build ----------------

__global__ void hist_kernel(const int* __restrict__ ei, int* __restrict__ deg, int E) {
    int e = blockIdx.x * 256 + threadIdx.x;
    if (e < E) atomicAdd(&deg[ei[E + e]], 1);
}

__global__ __launch_bounds__(1024) void scan_kernel(const int* __restrict__ deg,
                                                    int* __restrict__ offs,
                                                    float* __restrict__ dinv, int N) {
    __shared__ int sums[1024];
    int tid = threadIdx.x;
    int chunk = (N + 1023) / 1024;
    int start = tid * chunk;
    int end   = min(start + chunk, N);
    int s = 0;
    for (int i = start; i < end; ++i) s += deg[i];
    sums[tid] = s;
    __syncthreads();
    for (int off = 1; off < 1024; off <<= 1) {
        int v = 0;
        if (tid >= off) v = sums[tid - off];
        __syncthreads();
        sums[tid] += v;
        __syncthreads();
    }
    int run = sums[tid] - s;   // exclusive prefix
    for (int i = start; i < end; ++i) {
        offs[i] = run;
        run += deg[i];
        dinv[i] = rsqrtf((float)(deg[i] + 1));  // +1 self-loop
    }
    if (tid == 1023) offs[N] = sums[1023];
}

__global__ void fill_kernel(const int* __restrict__ ei, const int* __restrict__ offs,
                            int* __restrict__ cursor, int* __restrict__ csrc, int E) {
    int e = blockIdx.x * 256 + threadIdx.x;
    if (e < E) {
        int s = ei[e];
        int d = ei[E + e];
        int pos = offs[d] + atomicAdd(&cursor[d], 1);
        csrc[pos] = s;
    }
}

// ---------------- GEMM1: h1[M,256] = bf16(relu(x[M,512] @ W1[256,512]^T + b1)) ----------------
// bf16 MFMA 16x16x32, BM=128 BN=128 BK=32, 4 waves (2x2), wave tile 64x64 (4x4 frags).
// fp32 -> bf16 conversion happens in register staging; padded LDS stride avoids conflicts.

#define LDT 40   // ushorts per LDS row (32 + 8 pad) -> 80B stride, 16B-aligned frag reads

__global__ __launch_bounds__(256) void gemm1_bf16(const float* __restrict__ A,
                                                  const float* __restrict__ B,
                                                  const float* __restrict__ bias,
                                                  ushort* __restrict__ C,
                                                  int M) {
    constexpr int K = IN_DIM;      // 512
    constexpr int NK = K / 32;     // 16
    __shared__ ushort As[128 * LDT];
    __shared__ ushort Bs[128 * LDT];

    const int tid = threadIdx.x;
    const int lane = tid & 63;
    const int wid = tid >> 6;
    const int wm = wid >> 1, wn = wid & 1;
    const int m0 = blockIdx.y * 128;
    const int n0 = blockIdx.x * 128;
    const int l15 = lane & 15;
    const int koff = (lane >> 4) * 8;

    f32x4 acc[4][4];
#pragma unroll
    for (int i = 0; i < 4; ++i)
#pragma unroll
        for (int j = 0; j < 4; ++j) acc[i][j] = (f32x4)0.0f;

    float4 ra[4], rb[4];
    // prologue: load tile 0
#pragma unroll
    for (int i = 0; i < 4; ++i) {
        int slot = tid + i * 256;
        int row = slot >> 3, c4 = (slot & 7) << 2;
        int m = m0 + row;
        ra[i] = (m < M) ? *reinterpret_cast<const float4*>(&A[(size_t)m * K + c4])
                        : make_float4(0.f, 0.f, 0.f, 0.f);
        rb[i] = *reinterpret_cast<const float4*>(&B[(size_t)(n0 + row) * K + c4]);
    }
#pragma unroll
    for (int i = 0; i < 4; ++i) {
        int slot = tid + i * 256;
        int row = slot >> 3, c4 = (slot & 7) << 2;
        ushort4 ua = make_ushort4(f2b(ra[i].x), f2b(ra[i].y), f2b(ra[i].z), f2b(ra[i].w));
        ushort4 ub = make_ushort4(f2b(rb[i].x), f2b(rb[i].y), f2b(rb[i].z), f2b(rb[i].w));
        *reinterpret_cast<ushort4*>(&As[row * LDT + c4]) = ua;
        *reinterpret_cast<ushort4*>(&Bs[row * LDT + c4]) = ub;
    }
    __syncthreads();

    for (int ks = 0; ks < NK; ++ks) {
        // prefetch next K-tile into registers (hides HBM latency under MFMA)
        if (ks + 1 < NK) {
            int k0 = (ks + 1) * 32;
#pragma unroll
            for (int i = 0; i < 4; ++i) {
                int slot = tid + i * 256;
                int row = slot >> 3, c4 = (slot & 7) << 2;
                int m = m0 + row;
                ra[i] = (m < M) ? *reinterpret_cast<const float4*>(&A[(size_t)m * K + k0 + c4])
                                : make_float4(0.f, 0.f, 0.f, 0.f);
                rb[i] = *reinterpret_cast<const float4*>(&B[(size_t)(n0 + row) * K + k0 + c4]);
            }
        }
        // fragments + MFMA
        bf16x8 af[4], bf[4];
#pragma unroll
        for (int f = 0; f < 4; ++f) {
            af[f] = *reinterpret_cast<const bf16x8*>(&As[(wm * 64 + f * 16 + l15) * LDT + koff]);
            bf[f] = *reinterpret_cast<const bf16x8*>(&Bs[(wn * 64 + f * 16 + l15) * LDT + koff]);
        }
#pragma unroll
        for (int i = 0; i < 4; ++i)
#pragma unroll
            for (int j = 0; j < 4; ++j)
                acc[i][j] = __builtin_amdgcn_mfma_f32_16x16x32_bf16(af[i], bf[j], acc[i][j], 0, 0, 0);
        __syncthreads();
        if (ks + 1 < NK) {
#pragma unroll
            for (int i = 0; i < 4; ++i) {
                int slot = tid + i * 256;
                int row = slot >> 3, c4 = (slot & 7) << 2;
                ushort4 ua = make_ushort4(f2b(ra[i].x), f2b(ra[i].y), f2b(ra[i].z), f2b(ra[i].w));
                ushort4 ub = make_ushort4(f2b(rb[i].x), f2b(rb[i].y), f2b(rb[i].z), f2b(rb[i].w));
                *reinterpret_cast<ushort4*>(&As[row * LDT + c4]) = ua;
                *reinterpret_cast<ushort4*>(&Bs[row * LDT + c4]) = ub;
            }
            __syncthreads();
        }
    }

    // epilogue: bias + relu + bf16 store
    const int lr = (lane >> 4) * 2 * 2; // (lane>>4)*4
#pragma unroll
    for (int nf = 0; nf < 4; ++nf) {
        int col = n0 + wn * 64 + nf * 16 + l15;
        float bv = bias[col];
#pragma unroll
        for (int mf = 0; mf < 4; ++mf) {
#pragma unroll
            for (int j = 0; j < 4; ++j) {
                int row = m0 + wm * 64 + mf * 16 + lr + j;
                if (row < M) {
                    float v = acc[mf][nf][j] + bv;
                    v = fmaxf(v, 0.f);
                    C[(size_t)row * HID_DIM + col] = f2b(v);
                }
            }
        }
    }
}

// ---------------- GEMM2: h[M,64] = h1_bf16[M,256] @ W2[64,256]^T + b2 (fp32 out) ----------------
// BM=128 BN=64 BK=32, 4 waves (2x2), wave tile 64x32 (4x2 frags).

__global__ __launch_bounds__(256) void gemm2_bf16(const ushort* __restrict__ A,
                                                  const float* __restrict__ B,
                                                  const float* __restrict__ bias,
                                                  float* __restrict__ C,
                                                  int M) {
    constexpr int K = HID_DIM;     // 256
    constexpr int NK = K / 32;     // 8
    __shared__ ushort As[128 * LDT];
    __shared__ ushort Bs[64 * LDT];

    const int tid = threadIdx.x;
    const int lane = tid & 63;
    const int wid = tid >> 6;
    const int wm = wid >> 1, wn = wid & 1;
    const int m0 = blockIdx.x * 128;
    const int l15 = lane & 15;
    const int koff = (lane >> 4) * 8;

    f32x4 acc[4][2];
#pragma unroll
    for (int i = 0; i < 4; ++i)
#pragma unroll
        for (int j = 0; j < 2; ++j) acc[i][j] = (f32x4)0.0f;

    uint4 rawA[2];
    float4 rbv[2];
#pragma unroll
    for (int i = 0; i < 2; ++i) {
        int slot = tid + i * 256;
        int rowA = slot >> 2, c8 = (slot & 3) << 3;
        int m = m0 + rowA;
        rawA[i] = (m < M) ? *reinterpret_cast<const uint4*>(&A[(size_t)m * K + c8])
                          : make_uint4(0u, 0u, 0u, 0u);
        int rowB = slot >> 3, c4 = (slot & 7) << 2;
        rbv[i] = *reinterpret_cast<const float4*>(&B[(size_t)rowB * K + c4]);
    }
#pragma unroll
    for (int i = 0; i < 2; ++i) {
        int slot = tid + i * 256;
        int rowA = slot >> 2, c8 = (slot & 3) << 3;
        *reinterpret_cast<uint4*>(&As[rowA * LDT + c8]) = rawA[i];
        int rowB = slot >> 3, c4 = (slot & 7) << 2;
        ushort4 ub = make_ushort4(f2b(rbv[i].x), f2b(rbv[i].y), f2b(rbv[i].z), f2b(rbv[i].w));
        *reinterpret_cast<ushort4*>(&Bs[rowB * LDT + c4]) = ub;
    }
    __syncthreads();

    for (int ks = 0; ks < NK; ++ks) {
        if (ks + 1 < NK) {
            int k0 = (ks + 1) * 32;
#pragma unroll
            for (int i = 0; i < 2; ++i) {
                int slot = tid + i * 256;
                int rowA = slot >> 2, c8 = (slot & 3) << 3;
                int m = m0 + rowA;
                rawA[i] = (m < M) ? *reinterpret_cast<const uint4*>(&A[(size_t)m * K + k0 + c8])
                                  : make_uint4(0u, 0u, 0u, 0u);
                int rowB = slot >> 3, c4 = (slot & 7) << 2;
                rbv[i] = *reinterpret_cast<const float4*>(&B[(size_t)rowB * K + k0 + c4]);
            }
        }
        bf16x8 af[4], bf[2];
#pragma unroll
        for (int f = 0; f < 4; ++f)
            af[f] = *reinterpret_cast<const bf16x8*>(&As[(wm * 64 + f * 16 + l15) * LDT + koff]);
#pragma unroll
        for (int f = 0; f < 2; ++f)
            bf[f] = *reinterpret_cast<const bf16x8*>(&Bs[(wn * 32 + f * 16 + l15) * LDT + koff]);
#pragma unroll
        for (int i = 0; i < 4; ++i)
#pragma unroll
            for (int j = 0; j < 2; ++j)
                acc[i][j] = __builtin_amdgcn_mfma_f32_16x16x32_bf16(af[i], bf[j], acc[i][j], 0, 0, 0);
        __syncthreads();
        if (ks + 1 < NK) {
#pragma unroll
            for (int i = 0; i < 2; ++i) {
                int slot = tid + i * 256;
                int rowA = slot >> 2, c8 = (slot & 3) << 3;
                *reinterpret_cast<uint4*>(&As[rowA * LDT + c8]) = rawA[i];
                int rowB = slot >> 3, c4 = (slot & 7) << 2;
                ushort4 ub = make_ushort4(f2b(rbv[i].x), f2b(rbv[i].y), f2b(rbv[i].z), f2b(rbv[i].w));
                *reinterpret_cast<ushort4*>(&Bs[rowB * LDT + c4]) = ub;
            }
            __syncthreads();
        }
    }

    const int lr = (lane >> 4) * 4;
#pragma unroll
    for (int nf = 0; nf < 2; ++nf) {
        int col = wn * 32 + nf * 16 + l15;
        float bv = bias[col];
#pragma unroll
        for (int mf = 0; mf < 4; ++mf) {
#pragma unroll
            for (int j = 0; j < 4; ++j) {
                int row = m0 + wm * 64 + mf * 16 + lr + j;
                if (row < M)
                    C[(size_t)row * OUT_DIM + col] = acc[mf][nf][j] + bv;
            }
        }
    }
}

// ---------------- propagation: xout = 0.9 * (A_hat @ xin) + 0.1 * h ----------------

__global__ __launch_bounds__(256) void prop_kernel(const float* __restrict__ xin,
                                                   const float* __restrict__ h,
                                                   const float* __restrict__ dinv,
                                                   const int* __restrict__ offs,
                                                   const int* __restrict__ csrc,
                                                   float* __restrict__ xout, int N) {
    int node = blockIdx.x * 4 + (threadIdx.x >> 6);
    int lane = threadIdx.x & 63;
    if (node >= N) return;
    float di = dinv[node];
    float acc = di * di * xin[(size_t)node * 64 + lane];
    int e0 = offs[node], e1 = offs[node + 1];
    for (int e = e0; e < e1; ++e) {
        int s = csrc[e];
        float w = di * dinv[s];
        acc = fmaf(w, xin[(size_t)s * 64 + lane], acc);
    }
    xout[(size_t)node * 64 + lane] = 0.9f * acc + 0.1f * h[(size_t)node * 64 + lane];
}

// ---------------- log-softmax over 64 features (wave per node) ----------------

__global__ __launch_bounds__(256) void lsm_kernel(const float* __restrict__ xin,
                                                  float* __restrict__ out, int N) {
    int node = blockIdx.x * 4 + (threadIdx.x >> 6);
    int lane = threadIdx.x & 63;
    if (node >= N) return;
    float v = xin[(size_t)node * 64 + lane];
    float m = v;
    for (int o = 32; o > 0; o >>= 1) m = fmaxf(m, __shfl_xor(m, o));
    float ex = expf(v - m);
    float sum = ex;
    for (int o = 32; o > 0; o >>= 1) sum += __shfl_xor(sum, o);
    out[(size_t)node * 64 + lane] = v - m - logf(sum);
}

// ---------------- launch ----------------

static inline size_t align256(size_t x) { return (x + 255) & ~(size_t)255; }

extern "C" void kernel_launch(void* const* d_in, const int* in_sizes, int n_in,
                              void* d_out, int out_size, void* d_ws, size_t ws_size,
                              hipStream_t stream) {
    const float* x  = (const float*)d_in[0];
    const float* W1 = (const float*)d_in[1];
    const float* b1 = (const float*)d_in[2];
    const float* W2 = (const float*)d_in[3];
    const float* b2 = (const float*)d_in[4];
    const int*   ei = (const int*)d_in[5];

    const int N = in_sizes[0] / IN_DIM;
    const int E = in_sizes[5] / 2;

    char* base = (char*)d_ws;
    size_t off = 0;
    ushort* h1 = (ushort*)(base + off); off += align256((size_t)N * HID_DIM * 2);
    float* h    = (float*)(base + off); off += align256((size_t)N * OUT_DIM * 4);
    float* dinv = (float*)(base + off); off += align256((size_t)N * 4);
    int*   deg  = (int*)(base + off);   off += align256((size_t)N * 4);
    int*   offs = (int*)(base + off);   off += align256((size_t)(N + 1) * 4);
    int*   cur  = (int*)(base + off);   off += align256((size_t)N * 4);
    int*   csrc = (int*)(base + off);   off += align256((size_t)E * 4);
    float* xa   = (float*)h1;            // reuse h1 region after MLP done (12.8MB < 25.6MB)
    float* xo   = (float*)d_out;

    // ---- CSR build ----
    hipMemsetAsync(deg, 0, (size_t)N * 4, stream);
    hipMemsetAsync(cur, 0, (size_t)N * 4, stream);
    hist_kernel<<<(E + 255) / 256, 256, 0, stream>>>(ei, deg, E);
    scan_kernel<<<1, 1024, 0, stream>>>(deg, offs, dinv, N);
    fill_kernel<<<(E + 255) / 256, 256, 0, stream>>>(ei, offs, cur, csrc, E);

    // ---- MLP (bf16 MFMA) ----
    {
        dim3 g(HID_DIM / 128, (N + 127) / 128);
        gemm1_bf16<<<g, 256, 0, stream>>>(x, W1, b1, h1, N);
    }
    {
        dim3 g((N + 127) / 128);
        gemm2_bf16<<<g, 256, 0, stream>>>(h1, W2, b2, h, N);
    }

    // ---- K propagation steps (ping-pong: xa <-> d_out) ----
    int blocks = (N + 3) / 4;
    prop_kernel<<<blocks, 256, 0, stream>>>(h,  h, dinv, offs, csrc, xa, N);  // iter 1
    prop_kernel<<<blocks, 256, 0, stream>>>(xa, h, dinv, offs, csrc, xo, N);  // iter 2
    prop_kernel<<<blocks, 256, 0, stream>>>(xo, h, dinv, offs, csrc, xa, N);  // iter 3
    prop_kernel<<<blocks, 256, 0, stream>>>(xa, h, dinv, offs, csrc, xo, N);  // iter 4
    prop_kernel<<<blocks, 256, 0, stream>>>(xo, h, dinv, offs, csrc, xa, N);  // iter 5

    // ---- log-softmax ----
    lsm_kernel<<<blocks, 256, 0, stream>>>(xa, xo, N);
}

// Round 3
// 669.021 us; speedup vs baseline: 1.2487x; 1.0384x over previous
//
#include <hip/hip_runtime.h>
#include <hip/hip_bf16.h>

#define IN_DIM  512
#define HID_DIM 256
#define OUT_DIM 64

typedef __attribute__((ext_vector_type(8))) short bf16x8;
typedef __attribute__((ext_vector_type(4))) float f32x4;

static __device__ __forceinline__ ushort f2b(float f) {
    __hip_bfloat16 b = __float2bfloat16(f);
    return *reinterpret_cast<ushort*>(&b);
}

#define GLOAD16(g, l) __builtin_amdgcn_global_load_lds(                      \
    (const __attribute__((address_space(1))) void*)(g),                      \
    (__attribute__((address_space(3))) void*)(l), 16, 0, 0)

// ---------------- fp32 -> bf16 bulk convert (8 elems/thread/step) ----------------

__global__ __launch_bounds__(256) void f2b_kernel(const float* __restrict__ in,
                                                  ushort* __restrict__ out, int n8) {
    for (int i = blockIdx.x * 256 + threadIdx.x; i < n8; i += gridDim.x * 256) {
        float4 a = *reinterpret_cast<const float4*>(&in[(size_t)i * 8]);
        float4 b = *reinterpret_cast<const float4*>(&in[(size_t)i * 8 + 4]);
        ushort4 lo = make_ushort4(f2b(a.x), f2b(a.y), f2b(a.z), f2b(a.w));
        ushort4 hi = make_ushort4(f2b(b.x), f2b(b.y), f2b(b.z), f2b(b.w));
        *reinterpret_cast<ushort4*>(&out[(size_t)i * 8])     = lo;
        *reinterpret_cast<ushort4*>(&out[(size_t)i * 8 + 4]) = hi;
    }
}

// ---------------- CSR build ----------------

__global__ void hist_kernel(const int* __restrict__ ei, int* __restrict__ deg, int E) {
    int e = blockIdx.x * 256 + threadIdx.x;
    if (e < E) atomicAdd(&deg[ei[E + e]], 1);
}

__global__ __launch_bounds__(1024) void scan_kernel(const int* __restrict__ deg,
                                                    int* __restrict__ offs,
                                                    float* __restrict__ dinv, int N) {
    __shared__ int sums[1024];
    int tid = threadIdx.x;
    int chunk = (N + 1023) / 1024;
    int start = tid * chunk;
    int end   = min(start + chunk, N);
    int s = 0;
    for (int i = start; i < end; ++i) s += deg[i];
    sums[tid] = s;
    __syncthreads();
    for (int off = 1; off < 1024; off <<= 1) {
        int v = 0;
        if (tid >= off) v = sums[tid - off];
        __syncthreads();
        sums[tid] += v;
        __syncthreads();
    }
    int run = sums[tid] - s;   // exclusive prefix
    for (int i = start; i < end; ++i) {
        offs[i] = run;
        run += deg[i];
        dinv[i] = rsqrtf((float)(deg[i] + 1));  // +1 self-loop
    }
    if (tid == 1023) offs[N] = sums[1023];
}

__global__ void fill_kernel(const int* __restrict__ ei, const int* __restrict__ offs,
                            int* __restrict__ cursor, const float* __restrict__ dinv,
                            int* __restrict__ csrc, float* __restrict__ wcsr, int E) {
    int e = blockIdx.x * 256 + threadIdx.x;
    if (e < E) {
        int s = ei[e];
        int d = ei[E + e];
        int pos = offs[d] + atomicAdd(&cursor[d], 1);
        csrc[pos] = s;
        wcsr[pos] = dinv[d] * dinv[s];
    }
}

// ---------------- GEMM1: h1[M,256] = bf16(relu(xb[M,512] @ W1b[256,512]^T + b1)) ----
// Pure bf16 MFMA, m97 structure: global_load_lds(16B) staging, BK=64,
// XOR-swizzled LDS (pre-swizzled global source + swizzled ds_read), 2-barrier loop.
// BM=128 BN=128, 4 waves (2x2), wave tile 64x64 = 4x4 frags, 2 K-substeps.

__global__ __launch_bounds__(256) void gemm1_mfma(const ushort* __restrict__ A,
                                                  const ushort* __restrict__ B,
                                                  const float* __restrict__ bias,
                                                  ushort* __restrict__ C, int M) {
    constexpr int K = IN_DIM;       // 512
    constexpr int NK = K / 64;      // 8 K-steps
    __shared__ ushort As[128 * 64];
    __shared__ ushort Bs[128 * 64];

    const int tid  = threadIdx.x;
    const int lane = tid & 63;
    const int wid  = tid >> 6;
    const int wm = wid >> 1, wn = wid & 1;
    const int m0 = blockIdx.y * 128;
    const int n0 = blockIdx.x * 128;
    const int l15 = lane & 15;
    const int lq  = lane >> 4;           // 0..3

    // staging: instr (wid,q) covers rows [(wid*4+q)*8, +8); lane -> row l>>3, slot l&7.
    // LDS(row,slot) holds global (row, slot ^ (row&7)); rbase%8==0 so row&7 == l>>3.
    const int srow = lane >> 3;              // 0..7
    const int sslot = (lane & 7) ^ srow;     // pre-swizzled 16B source slot

    f32x4 acc[4][4];
#pragma unroll
    for (int i = 0; i < 4; ++i)
#pragma unroll
        for (int j = 0; j < 4; ++j) acc[i][j] = (f32x4)0.0f;

    for (int ks = 0; ks < NK; ++ks) {
        const int k0 = ks * 64;
#pragma unroll
        for (int q = 0; q < 4; ++q) {
            const int rbase = (wid * 4 + q) * 8;
            const int row = rbase + srow;
            int am = m0 + row; if (am >= M) am = M - 1;   // clamp: rows >= M unused
            const ushort* ga = A + (size_t)am * K + k0 + sslot * 8;
            const ushort* gb = B + (size_t)(n0 + row) * K + k0 + sslot * 8;
            GLOAD16(ga, &As[rbase * 64]);
            GLOAD16(gb, &Bs[rbase * 64]);
        }
        __syncthreads();   // compiler drains vmcnt(0) before s_barrier
#pragma unroll
        for (int kk = 0; kk < 2; ++kk) {
            bf16x8 af[4], bf[4];
#pragma unroll
            for (int f = 0; f < 4; ++f) {
                const int ar = wm * 64 + f * 16 + l15;
                const int br = wn * 64 + f * 16 + l15;
                const int slot = kk * 4 + lq;
                af[f] = *reinterpret_cast<const bf16x8*>(&As[ar * 64 + (slot ^ (ar & 7)) * 8]);
                bf[f] = *reinterpret_cast<const bf16x8*>(&Bs[br * 64 + (slot ^ (br & 7)) * 8]);
            }
#pragma unroll
            for (int i = 0; i < 4; ++i)
#pragma unroll
                for (int j = 0; j < 4; ++j)
                    acc[i][j] = __builtin_amdgcn_mfma_f32_16x16x32_bf16(af[i], bf[j], acc[i][j], 0, 0, 0);
        }
        __syncthreads();
    }

    // epilogue: bias + relu + bf16 store (C/D layout: col=lane&15, row=(lane>>4)*4+j)
    const int lr = lq * 4;
#pragma unroll
    for (int nf = 0; nf < 4; ++nf) {
        int col = n0 + wn * 64 + nf * 16 + l15;
        float bv = bias[col];
#pragma unroll
        for (int mf = 0; mf < 4; ++mf) {
#pragma unroll
            for (int j = 0; j < 4; ++j) {
                int row = m0 + wm * 64 + mf * 16 + lr + j;
                if (row < M) {
                    float v = fmaxf(acc[mf][nf][j] + bv, 0.f);
                    C[(size_t)row * HID_DIM + col] = f2b(v);
                }
            }
        }
    }
}

// ---------------- GEMM2: h[M,64] = h1_bf16[M,256] @ W2[64,256]^T + b2 (fp32 out) ----

#define LDT 40   // ushorts per LDS row (32 + 8 pad)

__global__ __launch_bounds__(256) void gemm2_bf16(const ushort* __restrict__ A,
                                                  const float* __restrict__ B,
                                                  const float* __restrict__ bias,
                                                  float* __restrict__ C,
                                                  int M) {
    constexpr int K = HID_DIM;     // 256
    constexpr int NK = K / 32;     // 8
    __shared__ ushort As[128 * LDT];
    __shared__ ushort Bs[64 * LDT];

    const int tid = threadIdx.x;
    const int lane = tid & 63;
    const int wid = tid >> 6;
    const int wm = wid >> 1, wn = wid & 1;
    const int m0 = blockIdx.x * 128;
    const int l15 = lane & 15;
    const int koff = (lane >> 4) * 8;

    f32x4 acc[4][2];
#pragma unroll
    for (int i = 0; i < 4; ++i)
#pragma unroll
        for (int j = 0; j < 2; ++j) acc[i][j] = (f32x4)0.0f;

    uint4 rawA[2];
    float4 rbv[2];
#pragma unroll
    for (int i = 0; i < 2; ++i) {
        int slot = tid + i * 256;
        int rowA = slot >> 2, c8 = (slot & 3) << 3;
        int m = m0 + rowA;
        rawA[i] = (m < M) ? *reinterpret_cast<const uint4*>(&A[(size_t)m * K + c8])
                          : make_uint4(0u, 0u, 0u, 0u);
        int rowB = slot >> 3, c4 = (slot & 7) << 2;
        rbv[i] = *reinterpret_cast<const float4*>(&B[(size_t)rowB * K + c4]);
    }
#pragma unroll
    for (int i = 0; i < 2; ++i) {
        int slot = tid + i * 256;
        int rowA = slot >> 2, c8 = (slot & 3) << 3;
        *reinterpret_cast<uint4*>(&As[rowA * LDT + c8]) = rawA[i];
        int rowB = slot >> 3, c4 = (slot & 7) << 2;
        ushort4 ub = make_ushort4(f2b(rbv[i].x), f2b(rbv[i].y), f2b(rbv[i].z), f2b(rbv[i].w));
        *reinterpret_cast<ushort4*>(&Bs[rowB * LDT + c4]) = ub;
    }
    __syncthreads();

    for (int ks = 0; ks < NK; ++ks) {
        if (ks + 1 < NK) {
            int k0 = (ks + 1) * 32;
#pragma unroll
            for (int i = 0; i < 2; ++i) {
                int slot = tid + i * 256;
                int rowA = slot >> 2, c8 = (slot & 3) << 3;
                int m = m0 + rowA;
                rawA[i] = (m < M) ? *reinterpret_cast<const uint4*>(&A[(size_t)m * K + k0 + c8])
                                  : make_uint4(0u, 0u, 0u, 0u);
                int rowB = slot >> 3, c4 = (slot & 7) << 2;
                rbv[i] = *reinterpret_cast<const float4*>(&B[(size_t)rowB * K + k0 + c4]);
            }
        }
        bf16x8 af[4], bf[2];
#pragma unroll
        for (int f = 0; f < 4; ++f)
            af[f] = *reinterpret_cast<const bf16x8*>(&As[(wm * 64 + f * 16 + l15) * LDT + koff]);
#pragma unroll
        for (int f = 0; f < 2; ++f)
            bf[f] = *reinterpret_cast<const bf16x8*>(&Bs[(wn * 32 + f * 16 + l15) * LDT + koff]);
#pragma unroll
        for (int i = 0; i < 4; ++i)
#pragma unroll
            for (int j = 0; j < 2; ++j)
                acc[i][j] = __builtin_amdgcn_mfma_f32_16x16x32_bf16(af[i], bf[j], acc[i][j], 0, 0, 0);
        __syncthreads();
        if (ks + 1 < NK) {
#pragma unroll
            for (int i = 0; i < 2; ++i) {
                int slot = tid + i * 256;
                int rowA = slot >> 2, c8 = (slot & 3) << 3;
                *reinterpret_cast<uint4*>(&As[rowA * LDT + c8]) = rawA[i];
                int rowB = slot >> 3, c4 = (slot & 7) << 2;
                ushort4 ub = make_ushort4(f2b(rbv[i].x), f2b(rbv[i].y), f2b(rbv[i].z), f2b(rbv[i].w));
                *reinterpret_cast<ushort4*>(&Bs[rowB * LDT + c4]) = ub;
            }
            __syncthreads();
        }
    }

    const int lr = (lane >> 4) * 4;
#pragma unroll
    for (int nf = 0; nf < 2; ++nf) {
        int col = wn * 32 + nf * 16 + l15;
        float bv = bias[col];
#pragma unroll
        for (int mf = 0; mf < 4; ++mf) {
#pragma unroll
            for (int j = 0; j < 4; ++j) {
                int row = m0 + wm * 64 + mf * 16 + lr + j;
                if (row < M)
                    C[(size_t)row * OUT_DIM + col] = acc[mf][nf][j] + bv;
            }
        }
    }
}

// ---------------- propagation: xout = 0.9 * (A_hat @ xin) + 0.1 * h ----------------

__global__ __launch_bounds__(256) void prop_kernel(const float* __restrict__ xin,
                                                   const float* __restrict__ h,
                                                   const float* __restrict__ dinv,
                                                   const int* __restrict__ offs,
                                                   const int* __restrict__ csrc,
                                                   const float* __restrict__ wcsr,
                                                   float* __restrict__ xout, int N) {
    int node = blockIdx.x * 4 + (threadIdx.x >> 6);
    int lane = threadIdx.x & 63;
    if (node >= N) return;
    float di = dinv[node];
    float acc = di * di * xin[(size_t)node * 64 + lane];
    int e0 = offs[node], e1 = offs[node + 1];
    for (int e = e0; e < e1; ++e)
        acc = fmaf(wcsr[e], xin[(size_t)csrc[e] * 64 + lane], acc);
    xout[(size_t)node * 64 + lane] = 0.9f * acc + 0.1f * h[(size_t)node * 64 + lane];
}

// ---------------- final propagation fused with log-softmax ----------------

__global__ __launch_bounds__(256) void prop_lsm_kernel(const float* __restrict__ xin,
                                                       const float* __restrict__ h,
                                                       const float* __restrict__ dinv,
                                                       const int* __restrict__ offs,
                                                       const int* __restrict__ csrc,
                                                       const float* __restrict__ wcsr,
                                                       float* __restrict__ out, int N) {
    int node = blockIdx.x * 4 + (threadIdx.x >> 6);
    int lane = threadIdx.x & 63;
    if (node >= N) return;
    float di = dinv[node];
    float acc = di * di * xin[(size_t)node * 64 + lane];
    int e0 = offs[node], e1 = offs[node + 1];
    for (int e = e0; e < e1; ++e)
        acc = fmaf(wcsr[e], xin[(size_t)csrc[e] * 64 + lane], acc);
    float v = 0.9f * acc + 0.1f * h[(size_t)node * 64 + lane];
    float m = v;
    for (int o = 32; o > 0; o >>= 1) m = fmaxf(m, __shfl_xor(m, o));
    float ex = expf(v - m);
    float sum = ex;
    for (int o = 32; o > 0; o >>= 1) sum += __shfl_xor(sum, o);
    out[(size_t)node * 64 + lane] = v - m - logf(sum);
}

// ---------------- launch ----------------

static inline size_t align256(size_t x) { return (x + 255) & ~(size_t)255; }

extern "C" void kernel_launch(void* const* d_in, const int* in_sizes, int n_in,
                              void* d_out, int out_size, void* d_ws, size_t ws_size,
                              hipStream_t stream) {
    const float* x  = (const float*)d_in[0];
    const float* W1 = (const float*)d_in[1];
    const float* b1 = (const float*)d_in[2];
    const float* W2 = (const float*)d_in[3];
    const float* b2 = (const float*)d_in[4];
    const int*   ei = (const int*)d_in[5];

    const int N = in_sizes[0] / IN_DIM;
    const int E = in_sizes[5] / 2;

    char* base = (char*)d_ws;
    size_t off = 0;
    ushort* xb  = (ushort*)(base + off); off += align256((size_t)N * IN_DIM * 2);        // 51.2MB
    ushort* w1b = (ushort*)(base + off); off += align256((size_t)HID_DIM * IN_DIM * 2);  // 256KB
    ushort* h1  = (ushort*)(base + off); off += align256((size_t)N * HID_DIM * 2);       // 25.6MB
    float* h    = (float*)(base + off);  off += align256((size_t)N * OUT_DIM * 4);       // 12.8MB
    float* dinv = (float*)(base + off);  off += align256((size_t)N * 4);
    int*   deg  = (int*)(base + off);    off += align256((size_t)N * 4);
    int*   offs = (int*)(base + off);    off += align256((size_t)(N + 1) * 4);
    int*   cur  = (int*)(base + off);    off += align256((size_t)N * 4);
    int*   csrc = (int*)(base + off);    off += align256((size_t)E * 4);                  // 3.2MB
    float* wcsr = (float*)(base + off);  off += align256((size_t)E * 4);                  // 3.2MB

    // state ping-pong buffers reuse the xb region (free after gemm1)
    float* xs0 = (float*)xb;
    float* xs1 = (float*)(xb + (size_t)N * OUT_DIM);  // +12.8MB into xb region

    // ---- CSR build ----
    hipMemsetAsync(deg, 0, (size_t)N * 4, stream);
    hipMemsetAsync(cur, 0, (size_t)N * 4, stream);
    hist_kernel<<<(E + 255) / 256, 256, 0, stream>>>(ei, deg, E);
    scan_kernel<<<1, 1024, 0, stream>>>(deg, offs, dinv, N);
    fill_kernel<<<(E + 255) / 256, 256, 0, stream>>>(ei, offs, cur, dinv, csrc, wcsr, E);

    // ---- bf16 conversion ----
    f2b_kernel<<<2048, 256, 0, stream>>>(x, xb, N * IN_DIM / 8);
    f2b_kernel<<<64, 256, 0, stream>>>(W1, w1b, HID_DIM * IN_DIM / 8);

    // ---- MLP (bf16 MFMA) ----
    {
        dim3 g(HID_DIM / 128, (N + 127) / 128);
        gemm1_mfma<<<g, 256, 0, stream>>>(xb, w1b, b1, h1, N);
    }
    {
        dim3 g((N + 127) / 128);
        gemm2_bf16<<<g, 256, 0, stream>>>(h1, W2, b2, h, N);
    }

    // ---- K propagation steps (ping-pong within old xb region; last fused w/ lsm) ----
    int blocks = (N + 3) / 4;
    prop_kernel<<<blocks, 256, 0, stream>>>(h,   h, dinv, offs, csrc, wcsr, xs0, N);  // 1
    prop_kernel<<<blocks, 256, 0, stream>>>(xs0, h, dinv, offs, csrc, wcsr, xs1, N);  // 2
    prop_kernel<<<blocks, 256, 0, stream>>>(xs1, h, dinv, offs, csrc, wcsr, xs0, N);  // 3
    prop_kernel<<<blocks, 256, 0, stream>>>(xs0, h, dinv, offs, csrc, wcsr, xs1, N);  // 4
    prop_lsm_kernel<<<blocks, 256, 0, stream>>>(xs1, h, dinv, offs, csrc, wcsr,
                                                (float*)d_out, N);                     // 5 + lsm
}

// Round 4
// 374.889 us; speedup vs baseline: 2.2284x; 1.7846x over previous
//
#include <hip/hip_runtime.h>
#include <hip/hip_bf16.h>

#define IN_DIM  512
#define HID_DIM 256
#define OUT_DIM 64

typedef __attribute__((ext_vector_type(8))) short bf16x8;
typedef __attribute__((ext_vector_type(4))) float f32x4;

static __device__ __forceinline__ ushort f2b(float f) {
    __hip_bfloat16 b = __float2bfloat16(f);
    return *reinterpret_cast<ushort*>(&b);
}

#define GLOAD16(g, l) __builtin_amdgcn_global_load_lds(                      \
    (const __attribute__((address_space(1))) void*)(g),                      \
    (__attribute__((address_space(3))) void*)(l), 16, 0, 0)

// ---------------- fp32 -> bf16 bulk convert (8 elems/thread/step) ----------------

__global__ __launch_bounds__(256) void f2b_kernel(const float* __restrict__ in,
                                                  ushort* __restrict__ out, int n8) {
    for (int i = blockIdx.x * 256 + threadIdx.x; i < n8; i += gridDim.x * 256) {
        float4 a = *reinterpret_cast<const float4*>(&in[(size_t)i * 8]);
        float4 b = *reinterpret_cast<const float4*>(&in[(size_t)i * 8 + 4]);
        ushort4 lo = make_ushort4(f2b(a.x), f2b(a.y), f2b(a.z), f2b(a.w));
        ushort4 hi = make_ushort4(f2b(b.x), f2b(b.y), f2b(b.z), f2b(b.w));
        *reinterpret_cast<ushort4*>(&out[(size_t)i * 8])     = lo;
        *reinterpret_cast<ushort4*>(&out[(size_t)i * 8 + 4]) = hi;
    }
}

// ---------------- CSR build ----------------

__global__ void hist_kernel(const int* __restrict__ ei, int* __restrict__ deg, int E) {
    int e = blockIdx.x * 256 + threadIdx.x;
    if (e < E) atomicAdd(&deg[ei[E + e]], 1);
}

// hierarchical exclusive scan over deg[N]: A) per-block scan, B) scan of block
// sums, C) add-back + dinv. N=50000 -> 196 blocks of 256.

__global__ __launch_bounds__(256) void scanA_kernel(const int* __restrict__ deg,
                                                    int* __restrict__ offs,
                                                    int* __restrict__ bsum, int N) {
    __shared__ int sh[256];
    int tid = threadIdx.x;
    int i = blockIdx.x * 256 + tid;
    int v = (i < N) ? deg[i] : 0;
    sh[tid] = v;
    __syncthreads();
#pragma unroll
    for (int off = 1; off < 256; off <<= 1) {
        int t = (tid >= off) ? sh[tid - off] : 0;
        __syncthreads();
        sh[tid] += t;
        __syncthreads();
    }
    if (i < N) offs[i] = sh[tid] - v;          // exclusive within block
    if (tid == 255) bsum[blockIdx.x] = sh[255]; // block total
}

__global__ __launch_bounds__(256) void scanB_kernel(int* __restrict__ bsum, int nb) {
    __shared__ int sh[256];
    int tid = threadIdx.x;
    int v = (tid < nb) ? bsum[tid] : 0;
    sh[tid] = v;
    __syncthreads();
#pragma unroll
    for (int off = 1; off < 256; off <<= 1) {
        int t = (tid >= off) ? sh[tid - off] : 0;
        __syncthreads();
        sh[tid] += t;
        __syncthreads();
    }
    if (tid < nb) bsum[tid] = sh[tid] - v;     // exclusive block prefix
}

__global__ __launch_bounds__(256) void scanC_kernel(const int* __restrict__ deg,
                                                    const int* __restrict__ bsum,
                                                    int* __restrict__ offs,
                                                    float* __restrict__ dinv,
                                                    int N, int E) {
    int i = blockIdx.x * 256 + threadIdx.x;
    if (i < N) {
        offs[i] += bsum[i >> 8];
        dinv[i] = rsqrtf((float)(deg[i] + 1));  // +1 self-loop
    }
    if (i == 0) offs[N] = E;
}

__global__ void fill_kernel(const int* __restrict__ ei, const int* __restrict__ offs,
                            int* __restrict__ cursor, const float* __restrict__ dinv,
                            int* __restrict__ csrc, float* __restrict__ wcsr, int E) {
    int e = blockIdx.x * 256 + threadIdx.x;
    if (e < E) {
        int s = ei[e];
        int d = ei[E + e];
        int pos = offs[d] + atomicAdd(&cursor[d], 1);
        csrc[pos] = s;
        wcsr[pos] = dinv[d] * dinv[s];
    }
}

// ---------------- GEMM1: h1[M,256] = bf16(relu(xb[M,512] @ W1b[256,512]^T + b1)) ----
// Pure bf16 MFMA, m97 structure: global_load_lds(16B) staging, BK=64,
// XOR-swizzled LDS (pre-swizzled global source + swizzled ds_read), 2-barrier loop.

__global__ __launch_bounds__(256) void gemm1_mfma(const ushort* __restrict__ A,
                                                  const ushort* __restrict__ B,
                                                  const float* __restrict__ bias,
                                                  ushort* __restrict__ C, int M) {
    constexpr int K = IN_DIM;       // 512
    constexpr int NK = K / 64;      // 8 K-steps
    __shared__ ushort As[128 * 64];
    __shared__ ushort Bs[128 * 64];

    const int tid  = threadIdx.x;
    const int lane = tid & 63;
    const int wid  = tid >> 6;
    const int wm = wid >> 1, wn = wid & 1;
    const int m0 = blockIdx.y * 128;
    const int n0 = blockIdx.x * 128;
    const int l15 = lane & 15;
    const int lq  = lane >> 4;           // 0..3

    const int srow = lane >> 3;              // 0..7
    const int sslot = (lane & 7) ^ srow;     // pre-swizzled 16B source slot

    f32x4 acc[4][4];
#pragma unroll
    for (int i = 0; i < 4; ++i)
#pragma unroll
        for (int j = 0; j < 4; ++j) acc[i][j] = (f32x4)0.0f;

    for (int ks = 0; ks < NK; ++ks) {
        const int k0 = ks * 64;
#pragma unroll
        for (int q = 0; q < 4; ++q) {
            const int rbase = (wid * 4 + q) * 8;
            const int row = rbase + srow;
            int am = m0 + row; if (am >= M) am = M - 1;   // clamp: rows >= M unused
            const ushort* ga = A + (size_t)am * K + k0 + sslot * 8;
            const ushort* gb = B + (size_t)(n0 + row) * K + k0 + sslot * 8;
            GLOAD16(ga, &As[rbase * 64]);
            GLOAD16(gb, &Bs[rbase * 64]);
        }
        __syncthreads();
#pragma unroll
        for (int kk = 0; kk < 2; ++kk) {
            bf16x8 af[4], bf[4];
#pragma unroll
            for (int f = 0; f < 4; ++f) {
                const int ar = wm * 64 + f * 16 + l15;
                const int br = wn * 64 + f * 16 + l15;
                const int slot = kk * 4 + lq;
                af[f] = *reinterpret_cast<const bf16x8*>(&As[ar * 64 + (slot ^ (ar & 7)) * 8]);
                bf[f] = *reinterpret_cast<const bf16x8*>(&Bs[br * 64 + (slot ^ (br & 7)) * 8]);
            }
#pragma unroll
            for (int i = 0; i < 4; ++i)
#pragma unroll
                for (int j = 0; j < 4; ++j)
                    acc[i][j] = __builtin_amdgcn_mfma_f32_16x16x32_bf16(af[i], bf[j], acc[i][j], 0, 0, 0);
        }
        __syncthreads();
    }

    const int lr = lq * 4;
#pragma unroll
    for (int nf = 0; nf < 4; ++nf) {
        int col = n0 + wn * 64 + nf * 16 + l15;
        float bv = bias[col];
#pragma unroll
        for (int mf = 0; mf < 4; ++mf) {
#pragma unroll
            for (int j = 0; j < 4; ++j) {
                int row = m0 + wm * 64 + mf * 16 + lr + j;
                if (row < M) {
                    float v = fmaxf(acc[mf][nf][j] + bv, 0.f);
                    C[(size_t)row * HID_DIM + col] = f2b(v);
                }
            }
        }
    }
}

// ---------------- GEMM2: h[M,64] = h1_bf16[M,256] @ W2[64,256]^T + b2 (fp32 out) ----

#define LDT 40   // ushorts per LDS row (32 + 8 pad)

__global__ __launch_bounds__(256) void gemm2_bf16(const ushort* __restrict__ A,
                                                  const float* __restrict__ B,
                                                  const float* __restrict__ bias,
                                                  float* __restrict__ C,
                                                  int M) {
    constexpr int K = HID_DIM;     // 256
    constexpr int NK = K / 32;     // 8
    __shared__ ushort As[128 * LDT];
    __shared__ ushort Bs[64 * LDT];

    const int tid = threadIdx.x;
    const int lane = tid & 63;
    const int wid = tid >> 6;
    const int wm = wid >> 1, wn = wid & 1;
    const int m0 = blockIdx.x * 128;
    const int l15 = lane & 15;
    const int koff = (lane >> 4) * 8;

    f32x4 acc[4][2];
#pragma unroll
    for (int i = 0; i < 4; ++i)
#pragma unroll
        for (int j = 0; j < 2; ++j) acc[i][j] = (f32x4)0.0f;

    uint4 rawA[2];
    float4 rbv[2];
#pragma unroll
    for (int i = 0; i < 2; ++i) {
        int slot = tid + i * 256;
        int rowA = slot >> 2, c8 = (slot & 3) << 3;
        int m = m0 + rowA;
        rawA[i] = (m < M) ? *reinterpret_cast<const uint4*>(&A[(size_t)m * K + c8])
                          : make_uint4(0u, 0u, 0u, 0u);
        int rowB = slot >> 3, c4 = (slot & 7) << 2;
        rbv[i] = *reinterpret_cast<const float4*>(&B[(size_t)rowB * K + c4]);
    }
#pragma unroll
    for (int i = 0; i < 2; ++i) {
        int slot = tid + i * 256;
        int rowA = slot >> 2, c8 = (slot & 3) << 3;
        *reinterpret_cast<uint4*>(&As[rowA * LDT + c8]) = rawA[i];
        int rowB = slot >> 3, c4 = (slot & 7) << 2;
        ushort4 ub = make_ushort4(f2b(rbv[i].x), f2b(rbv[i].y), f2b(rbv[i].z), f2b(rbv[i].w));
        *reinterpret_cast<ushort4*>(&Bs[rowB * LDT + c4]) = ub;
    }
    __syncthreads();

    for (int ks = 0; ks < NK; ++ks) {
        if (ks + 1 < NK) {
            int k0 = (ks + 1) * 32;
#pragma unroll
            for (int i = 0; i < 2; ++i) {
                int slot = tid + i * 256;
                int rowA = slot >> 2, c8 = (slot & 3) << 3;
                int m = m0 + rowA;
                rawA[i] = (m < M) ? *reinterpret_cast<const uint4*>(&A[(size_t)m * K + k0 + c8])
                                  : make_uint4(0u, 0u, 0u, 0u);
                int rowB = slot >> 3, c4 = (slot & 7) << 2;
                rbv[i] = *reinterpret_cast<const float4*>(&B[(size_t)rowB * K + k0 + c4]);
            }
        }
        bf16x8 af[4], bf[2];
#pragma unroll
        for (int f = 0; f < 4; ++f)
            af[f] = *reinterpret_cast<const bf16x8*>(&As[(wm * 64 + f * 16 + l15) * LDT + koff]);
#pragma unroll
        for (int f = 0; f < 2; ++f)
            bf[f] = *reinterpret_cast<const bf16x8*>(&Bs[(wn * 32 + f * 16 + l15) * LDT + koff]);
#pragma unroll
        for (int i = 0; i < 4; ++i)
#pragma unroll
            for (int j = 0; j < 2; ++j)
                acc[i][j] = __builtin_amdgcn_mfma_f32_16x16x32_bf16(af[i], bf[j], acc[i][j], 0, 0, 0);
        __syncthreads();
        if (ks + 1 < NK) {
#pragma unroll
            for (int i = 0; i < 2; ++i) {
                int slot = tid + i * 256;
                int rowA = slot >> 2, c8 = (slot & 3) << 3;
                *reinterpret_cast<uint4*>(&As[rowA * LDT + c8]) = rawA[i];
                int rowB = slot >> 3, c4 = (slot & 7) << 2;
                ushort4 ub = make_ushort4(f2b(rbv[i].x), f2b(rbv[i].y), f2b(rbv[i].z), f2b(rbv[i].w));
                *reinterpret_cast<ushort4*>(&Bs[rowB * LDT + c4]) = ub;
            }
            __syncthreads();
        }
    }

    const int lr = (lane >> 4) * 4;
#pragma unroll
    for (int nf = 0; nf < 2; ++nf) {
        int col = wn * 32 + nf * 16 + l15;
        float bv = bias[col];
#pragma unroll
        for (int mf = 0; mf < 4; ++mf) {
#pragma unroll
            for (int j = 0; j < 4; ++j) {
                int row = m0 + wm * 64 + mf * 16 + lr + j;
                if (row < M)
                    C[(size_t)row * OUT_DIM + col] = acc[mf][nf][j] + bv;
            }
        }
    }
}

// ---------------- propagation: xout = 0.9 * (A_hat @ xin) + 0.1 * h ----------------
// unroll-8 with independent accumulators: 8 outstanding 256B gathers per wave.

__global__ __launch_bounds__(256) void prop_kernel(const float* __restrict__ xin,
                                                   const float* __restrict__ h,
                                                   const float* __restrict__ dinv,
                                                   const int* __restrict__ offs,
                                                   const int* __restrict__ csrc,
                                                   const float* __restrict__ wcsr,
                                                   float* __restrict__ xout, int N) {
    int node = blockIdx.x * 4 + (threadIdx.x >> 6);
    int lane = threadIdx.x & 63;
    if (node >= N) return;
    float di = dinv[node];
    float a0 = di * di * xin[(size_t)node * 64 + lane];
    float a1 = 0.f, a2 = 0.f, a3 = 0.f, a4 = 0.f, a5 = 0.f, a6 = 0.f, a7 = 0.f;
    int e0 = offs[node], e1 = offs[node + 1];
    int e = e0;
    for (; e + 8 <= e1; e += 8) {
        int   s0 = csrc[e+0], s1 = csrc[e+1], s2 = csrc[e+2], s3 = csrc[e+3];
        int   s4 = csrc[e+4], s5 = csrc[e+5], s6 = csrc[e+6], s7 = csrc[e+7];
        float w0 = wcsr[e+0], w1 = wcsr[e+1], w2 = wcsr[e+2], w3 = wcsr[e+3];
        float w4 = wcsr[e+4], w5 = wcsr[e+5], w6 = wcsr[e+6], w7 = wcsr[e+7];
        a0 = fmaf(w0, xin[(size_t)s0 * 64 + lane], a0);
        a1 = fmaf(w1, xin[(size_t)s1 * 64 + lane], a1);
        a2 = fmaf(w2, xin[(size_t)s2 * 64 + lane], a2);
        a3 = fmaf(w3, xin[(size_t)s3 * 64 + lane], a3);
        a4 = fmaf(w4, xin[(size_t)s4 * 64 + lane], a4);
        a5 = fmaf(w5, xin[(size_t)s5 * 64 + lane], a5);
        a6 = fmaf(w6, xin[(size_t)s6 * 64 + lane], a6);
        a7 = fmaf(w7, xin[(size_t)s7 * 64 + lane], a7);
    }
    for (; e < e1; ++e)
        a0 = fmaf(wcsr[e], xin[(size_t)csrc[e] * 64 + lane], a0);
    float acc = ((a0 + a1) + (a2 + a3)) + ((a4 + a5) + (a6 + a7));
    xout[(size_t)node * 64 + lane] = 0.9f * acc + 0.1f * h[(size_t)node * 64 + lane];
}

// ---------------- final propagation fused with log-softmax ----------------

__global__ __launch_bounds__(256) void prop_lsm_kernel(const float* __restrict__ xin,
                                                       const float* __restrict__ h,
                                                       const float* __restrict__ dinv,
                                                       const int* __restrict__ offs,
                                                       const int* __restrict__ csrc,
                                                       const float* __restrict__ wcsr,
                                                       float* __restrict__ out, int N) {
    int node = blockIdx.x * 4 + (threadIdx.x >> 6);
    int lane = threadIdx.x & 63;
    if (node >= N) return;
    float di = dinv[node];
    float a0 = di * di * xin[(size_t)node * 64 + lane];
    float a1 = 0.f, a2 = 0.f, a3 = 0.f, a4 = 0.f, a5 = 0.f, a6 = 0.f, a7 = 0.f;
    int e0 = offs[node], e1 = offs[node + 1];
    int e = e0;
    for (; e + 8 <= e1; e += 8) {
        int   s0 = csrc[e+0], s1 = csrc[e+1], s2 = csrc[e+2], s3 = csrc[e+3];
        int   s4 = csrc[e+4], s5 = csrc[e+5], s6 = csrc[e+6], s7 = csrc[e+7];
        float w0 = wcsr[e+0], w1 = wcsr[e+1], w2 = wcsr[e+2], w3 = wcsr[e+3];
        float w4 = wcsr[e+4], w5 = wcsr[e+5], w6 = wcsr[e+6], w7 = wcsr[e+7];
        a0 = fmaf(w0, xin[(size_t)s0 * 64 + lane], a0);
        a1 = fmaf(w1, xin[(size_t)s1 * 64 + lane], a1);
        a2 = fmaf(w2, xin[(size_t)s2 * 64 + lane], a2);
        a3 = fmaf(w3, xin[(size_t)s3 * 64 + lane], a3);
        a4 = fmaf(w4, xin[(size_t)s4 * 64 + lane], a4);
        a5 = fmaf(w5, xin[(size_t)s5 * 64 + lane], a5);
        a6 = fmaf(w6, xin[(size_t)s6 * 64 + lane], a6);
        a7 = fmaf(w7, xin[(size_t)s7 * 64 + lane], a7);
    }
    for (; e < e1; ++e)
        a0 = fmaf(wcsr[e], xin[(size_t)csrc[e] * 64 + lane], a0);
    float acc = ((a0 + a1) + (a2 + a3)) + ((a4 + a5) + (a6 + a7));
    float v = 0.9f * acc + 0.1f * h[(size_t)node * 64 + lane];
    float m = v;
    for (int o = 32; o > 0; o >>= 1) m = fmaxf(m, __shfl_xor(m, o));
    float ex = expf(v - m);
    float sum = ex;
    for (int o = 32; o > 0; o >>= 1) sum += __shfl_xor(sum, o);
    out[(size_t)node * 64 + lane] = v - m - logf(sum);
}

// ---------------- launch ----------------

static inline size_t align256(size_t x) { return (x + 255) & ~(size_t)255; }

extern "C" void kernel_launch(void* const* d_in, const int* in_sizes, int n_in,
                              void* d_out, int out_size, void* d_ws, size_t ws_size,
                              hipStream_t stream) {
    const float* x  = (const float*)d_in[0];
    const float* W1 = (const float*)d_in[1];
    const float* b1 = (const float*)d_in[2];
    const float* W2 = (const float*)d_in[3];
    const float* b2 = (const float*)d_in[4];
    const int*   ei = (const int*)d_in[5];

    const int N = in_sizes[0] / IN_DIM;
    const int E = in_sizes[5] / 2;
    const int nb = (N + 255) / 256;

    char* base = (char*)d_ws;
    size_t off = 0;
    ushort* xb  = (ushort*)(base + off); off += align256((size_t)N * IN_DIM * 2);        // 51.2MB
    ushort* w1b = (ushort*)(base + off); off += align256((size_t)HID_DIM * IN_DIM * 2);  // 256KB
    ushort* h1  = (ushort*)(base + off); off += align256((size_t)N * HID_DIM * 2);       // 25.6MB
    float* h    = (float*)(base + off);  off += align256((size_t)N * OUT_DIM * 4);       // 12.8MB
    float* dinv = (float*)(base + off);  off += align256((size_t)N * 4);
    int*   deg  = (int*)(base + off);    off += align256((size_t)N * 4);
    int*   offs = (int*)(base + off);    off += align256((size_t)(N + 1) * 4);
    int*   cur  = (int*)(base + off);    off += align256((size_t)N * 4);
    int*   bsum = (int*)(base + off);    off += align256((size_t)nb * 4);
    int*   csrc = (int*)(base + off);    off += align256((size_t)E * 4);                  // 3.2MB
    float* wcsr = (float*)(base + off);  off += align256((size_t)E * 4);                  // 3.2MB

    // state ping-pong buffers reuse the xb region (free after gemm1)
    float* xs0 = (float*)xb;
    float* xs1 = (float*)(xb + (size_t)N * OUT_DIM);  // +12.8MB into xb region

    // ---- CSR build ----
    hipMemsetAsync(deg, 0, (size_t)N * 4, stream);
    hipMemsetAsync(cur, 0, (size_t)N * 4, stream);
    hist_kernel<<<(E + 255) / 256, 256, 0, stream>>>(ei, deg, E);
    scanA_kernel<<<nb, 256, 0, stream>>>(deg, offs, bsum, N);
    scanB_kernel<<<1, 256, 0, stream>>>(bsum, nb);
    scanC_kernel<<<nb, 256, 0, stream>>>(deg, bsum, offs, dinv, N, E);
    fill_kernel<<<(E + 255) / 256, 256, 0, stream>>>(ei, offs, cur, dinv, csrc, wcsr, E);

    // ---- bf16 conversion ----
    f2b_kernel<<<2048, 256, 0, stream>>>(x, xb, N * IN_DIM / 8);
    f2b_kernel<<<64, 256, 0, stream>>>(W1, w1b, HID_DIM * IN_DIM / 8);

    // ---- MLP (bf16 MFMA) ----
    {
        dim3 g(HID_DIM / 128, (N + 127) / 128);
        gemm1_mfma<<<g, 256, 0, stream>>>(xb, w1b, b1, h1, N);
    }
    {
        dim3 g((N + 127) / 128);
        gemm2_bf16<<<g, 256, 0, stream>>>(h1, W2, b2, h, N);
    }

    // ---- K propagation steps (ping-pong within old xb region; last fused w/ lsm) ----
    int blocks = (N + 3) / 4;
    prop_kernel<<<blocks, 256, 0, stream>>>(h,   h, dinv, offs, csrc, wcsr, xs0, N);  // 1
    prop_kernel<<<blocks, 256, 0, stream>>>(xs0, h, dinv, offs, csrc, wcsr, xs1, N);  // 2
    prop_kernel<<<blocks, 256, 0, stream>>>(xs1, h, dinv, offs, csrc, wcsr, xs0, N);  // 3
    prop_kernel<<<blocks, 256, 0, stream>>>(xs0, h, dinv, offs, csrc, wcsr, xs1, N);  // 4
    prop_lsm_kernel<<<blocks, 256, 0, stream>>>(xs1, h, dinv, offs, csrc, wcsr,
                                                (float*)d_out, N);                     // 5 + lsm
}

// Round 5
// 329.399 us; speedup vs baseline: 2.5361x; 1.1381x over previous
//
#include <hip/hip_runtime.h>
#include <hip/hip_bf16.h>

#define IN_DIM  512
#define HID_DIM 256
#define OUT_DIM 64

typedef __attribute__((ext_vector_type(8))) short bf16x8;
typedef __attribute__((ext_vector_type(4))) float f32x4;

static __device__ __forceinline__ ushort f2b(float f) {
    __hip_bfloat16 b = __float2bfloat16(f);
    return *reinterpret_cast<ushort*>(&b);
}
static __device__ __forceinline__ float b2f_lo(uint u) {
    union { uint u; float f; } t; t.u = u << 16; return t.f;
}
static __device__ __forceinline__ float b2f_hi(uint u) {
    union { uint u; float f; } t; t.u = u & 0xFFFF0000u; return t.f;
}
static __device__ __forceinline__ uint packbf(float x, float y) {
    return (uint)f2b(x) | ((uint)f2b(y) << 16);
}

#define GLOAD16(g, l) __builtin_amdgcn_global_load_lds(                      \
    (const __attribute__((address_space(1))) void*)(g),                      \
    (__attribute__((address_space(3))) void*)(l), 16, 0, 0)

// ---------------- fp32 -> bf16 bulk convert (8 elems/thread/step) ----------------

__global__ __launch_bounds__(256) void f2b_kernel(const float* __restrict__ in,
                                                  ushort* __restrict__ out, int n8) {
    for (int i = blockIdx.x * 256 + threadIdx.x; i < n8; i += gridDim.x * 256) {
        float4 a = *reinterpret_cast<const float4*>(&in[(size_t)i * 8]);
        float4 b = *reinterpret_cast<const float4*>(&in[(size_t)i * 8 + 4]);
        ushort4 lo = make_ushort4(f2b(a.x), f2b(a.y), f2b(a.z), f2b(a.w));
        ushort4 hi = make_ushort4(f2b(b.x), f2b(b.y), f2b(b.z), f2b(b.w));
        *reinterpret_cast<ushort4*>(&out[(size_t)i * 8])     = lo;
        *reinterpret_cast<ushort4*>(&out[(size_t)i * 8 + 4]) = hi;
    }
}

// ---------------- CSR build ----------------

__global__ void hist_kernel(const int* __restrict__ ei, int* __restrict__ deg, int E) {
    int e = blockIdx.x * 256 + threadIdx.x;
    if (e < E) atomicAdd(&deg[ei[E + e]], 1);
}

// hierarchical exclusive scan over deg[N]

__global__ __launch_bounds__(256) void scanA_kernel(const int* __restrict__ deg,
                                                    int* __restrict__ offs,
                                                    int* __restrict__ bsum, int N) {
    __shared__ int sh[256];
    int tid = threadIdx.x;
    int i = blockIdx.x * 256 + tid;
    int v = (i < N) ? deg[i] : 0;
    sh[tid] = v;
    __syncthreads();
#pragma unroll
    for (int off = 1; off < 256; off <<= 1) {
        int t = (tid >= off) ? sh[tid - off] : 0;
        __syncthreads();
        sh[tid] += t;
        __syncthreads();
    }
    if (i < N) offs[i] = sh[tid] - v;
    if (tid == 255) bsum[blockIdx.x] = sh[255];
}

__global__ __launch_bounds__(256) void scanB_kernel(int* __restrict__ bsum, int nb) {
    __shared__ int sh[256];
    int tid = threadIdx.x;
    int v = (tid < nb) ? bsum[tid] : 0;
    sh[tid] = v;
    __syncthreads();
#pragma unroll
    for (int off = 1; off < 256; off <<= 1) {
        int t = (tid >= off) ? sh[tid - off] : 0;
        __syncthreads();
        sh[tid] += t;
        __syncthreads();
    }
    if (tid < nb) bsum[tid] = sh[tid] - v;
}

__global__ __launch_bounds__(256) void scanC_kernel(const int* __restrict__ deg,
                                                    const int* __restrict__ bsum,
                                                    int* __restrict__ offs,
                                                    float* __restrict__ dinv,
                                                    int N, int E) {
    int i = blockIdx.x * 256 + threadIdx.x;
    if (i < N) {
        offs[i] += bsum[i >> 8];
        dinv[i] = rsqrtf((float)(deg[i] + 1));
    }
    if (i == 0) offs[N] = E;
}

// edat[pos] = {src, bits(w)} -- one 8B load per edge in prop
__global__ void fill_kernel(const int* __restrict__ ei, const int* __restrict__ offs,
                            int* __restrict__ cursor, const float* __restrict__ dinv,
                            int2* __restrict__ edat, int E) {
    int e = blockIdx.x * 256 + threadIdx.x;
    if (e < E) {
        int s = ei[e];
        int d = ei[E + e];
        int pos = offs[d] + atomicAdd(&cursor[d], 1);
        edat[pos] = make_int2(s, __float_as_int(dinv[d] * dinv[s]));
    }
}

// ---------------- GEMM1: h1[M,256] = bf16(relu(xb[M,512] @ W1b[256,512]^T + b1)) ----

__global__ __launch_bounds__(256) void gemm1_mfma(const ushort* __restrict__ A,
                                                  const ushort* __restrict__ B,
                                                  const float* __restrict__ bias,
                                                  ushort* __restrict__ C, int M) {
    constexpr int K = IN_DIM;
    constexpr int NK = K / 64;
    __shared__ ushort As[128 * 64];
    __shared__ ushort Bs[128 * 64];

    const int tid  = threadIdx.x;
    const int lane = tid & 63;
    const int wid  = tid >> 6;
    const int wm = wid >> 1, wn = wid & 1;
    const int m0 = blockIdx.y * 128;
    const int n0 = blockIdx.x * 128;
    const int l15 = lane & 15;
    const int lq  = lane >> 4;

    const int srow = lane >> 3;
    const int sslot = (lane & 7) ^ srow;

    f32x4 acc[4][4];
#pragma unroll
    for (int i = 0; i < 4; ++i)
#pragma unroll
        for (int j = 0; j < 4; ++j) acc[i][j] = (f32x4)0.0f;

    for (int ks = 0; ks < NK; ++ks) {
        const int k0 = ks * 64;
#pragma unroll
        for (int q = 0; q < 4; ++q) {
            const int rbase = (wid * 4 + q) * 8;
            const int row = rbase + srow;
            int am = m0 + row; if (am >= M) am = M - 1;
            const ushort* ga = A + (size_t)am * K + k0 + sslot * 8;
            const ushort* gb = B + (size_t)(n0 + row) * K + k0 + sslot * 8;
            GLOAD16(ga, &As[rbase * 64]);
            GLOAD16(gb, &Bs[rbase * 64]);
        }
        __syncthreads();
#pragma unroll
        for (int kk = 0; kk < 2; ++kk) {
            bf16x8 af[4], bf[4];
#pragma unroll
            for (int f = 0; f < 4; ++f) {
                const int ar = wm * 64 + f * 16 + l15;
                const int br = wn * 64 + f * 16 + l15;
                const int slot = kk * 4 + lq;
                af[f] = *reinterpret_cast<const bf16x8*>(&As[ar * 64 + (slot ^ (ar & 7)) * 8]);
                bf[f] = *reinterpret_cast<const bf16x8*>(&Bs[br * 64 + (slot ^ (br & 7)) * 8]);
            }
#pragma unroll
            for (int i = 0; i < 4; ++i)
#pragma unroll
                for (int j = 0; j < 4; ++j)
                    acc[i][j] = __builtin_amdgcn_mfma_f32_16x16x32_bf16(af[i], bf[j], acc[i][j], 0, 0, 0);
        }
        __syncthreads();
    }

    const int lr = lq * 4;
#pragma unroll
    for (int nf = 0; nf < 4; ++nf) {
        int col = n0 + wn * 64 + nf * 16 + l15;
        float bv = bias[col];
#pragma unroll
        for (int mf = 0; mf < 4; ++mf) {
#pragma unroll
            for (int j = 0; j < 4; ++j) {
                int row = m0 + wm * 64 + mf * 16 + lr + j;
                if (row < M) {
                    float v = fmaxf(acc[mf][nf][j] + bv, 0.f);
                    C[(size_t)row * HID_DIM + col] = f2b(v);
                }
            }
        }
    }
}

// ---------------- GEMM2: h[M,64] = h1_bf16[M,256] @ W2[64,256]^T + b2 (fp32 out) ----

#define LDT 40

__global__ __launch_bounds__(256) void gemm2_bf16(const ushort* __restrict__ A,
                                                  const float* __restrict__ B,
                                                  const float* __restrict__ bias,
                                                  float* __restrict__ C,
                                                  int M) {
    constexpr int K = HID_DIM;
    constexpr int NK = K / 32;
    __shared__ ushort As[128 * LDT];
    __shared__ ushort Bs[64 * LDT];

    const int tid = threadIdx.x;
    const int lane = tid & 63;
    const int wid = tid >> 6;
    const int wm = wid >> 1, wn = wid & 1;
    const int m0 = blockIdx.x * 128;
    const int l15 = lane & 15;
    const int koff = (lane >> 4) * 8;

    f32x4 acc[4][2];
#pragma unroll
    for (int i = 0; i < 4; ++i)
#pragma unroll
        for (int j = 0; j < 2; ++j) acc[i][j] = (f32x4)0.0f;

    uint4 rawA[2];
    float4 rbv[2];
#pragma unroll
    for (int i = 0; i < 2; ++i) {
        int slot = tid + i * 256;
        int rowA = slot >> 2, c8 = (slot & 3) << 3;
        int m = m0 + rowA;
        rawA[i] = (m < M) ? *reinterpret_cast<const uint4*>(&A[(size_t)m * K + c8])
                          : make_uint4(0u, 0u, 0u, 0u);
        int rowB = slot >> 3, c4 = (slot & 7) << 2;
        rbv[i] = *reinterpret_cast<const float4*>(&B[(size_t)rowB * K + c4]);
    }
#pragma unroll
    for (int i = 0; i < 2; ++i) {
        int slot = tid + i * 256;
        int rowA = slot >> 2, c8 = (slot & 3) << 3;
        *reinterpret_cast<uint4*>(&As[rowA * LDT + c8]) = rawA[i];
        int rowB = slot >> 3, c4 = (slot & 7) << 2;
        ushort4 ub = make_ushort4(f2b(rbv[i].x), f2b(rbv[i].y), f2b(rbv[i].z), f2b(rbv[i].w));
        *reinterpret_cast<ushort4*>(&Bs[rowB * LDT + c4]) = ub;
    }
    __syncthreads();

    for (int ks = 0; ks < NK; ++ks) {
        if (ks + 1 < NK) {
            int k0 = (ks + 1) * 32;
#pragma unroll
            for (int i = 0; i < 2; ++i) {
                int slot = tid + i * 256;
                int rowA = slot >> 2, c8 = (slot & 3) << 3;
                int m = m0 + rowA;
                rawA[i] = (m < M) ? *reinterpret_cast<const uint4*>(&A[(size_t)m * K + k0 + c8])
                                  : make_uint4(0u, 0u, 0u, 0u);
                int rowB = slot >> 3, c4 = (slot & 7) << 2;
                rbv[i] = *reinterpret_cast<const float4*>(&B[(size_t)rowB * K + k0 + c4]);
            }
        }
        bf16x8 af[4], bf[2];
#pragma unroll
        for (int f = 0; f < 4; ++f)
            af[f] = *reinterpret_cast<const bf16x8*>(&As[(wm * 64 + f * 16 + l15) * LDT + koff]);
#pragma unroll
        for (int f = 0; f < 2; ++f)
            bf[f] = *reinterpret_cast<const bf16x8*>(&Bs[(wn * 32 + f * 16 + l15) * LDT + koff]);
#pragma unroll
        for (int i = 0; i < 4; ++i)
#pragma unroll
            for (int j = 0; j < 2; ++j)
                acc[i][j] = __builtin_amdgcn_mfma_f32_16x16x32_bf16(af[i], bf[j], acc[i][j], 0, 0, 0);
        __syncthreads();
        if (ks + 1 < NK) {
#pragma unroll
            for (int i = 0; i < 2; ++i) {
                int slot = tid + i * 256;
                int rowA = slot >> 2, c8 = (slot & 3) << 3;
                *reinterpret_cast<uint4*>(&As[rowA * LDT + c8]) = rawA[i];
                int rowB = slot >> 3, c4 = (slot & 7) << 2;
                ushort4 ub = make_ushort4(f2b(rbv[i].x), f2b(rbv[i].y), f2b(rbv[i].z), f2b(rbv[i].w));
                *reinterpret_cast<ushort4*>(&Bs[rowB * LDT + c4]) = ub;
            }
            __syncthreads();
        }
    }

    const int lr = (lane >> 4) * 4;
#pragma unroll
    for (int nf = 0; nf < 2; ++nf) {
        int col = wn * 32 + nf * 16 + l15;
        float bv = bias[col];
#pragma unroll
        for (int mf = 0; mf < 4; ++mf) {
#pragma unroll
            for (int j = 0; j < 4; ++j) {
                int row = m0 + wm * 64 + mf * 16 + lr + j;
                if (row < M)
                    C[(size_t)row * OUT_DIM + col] = acc[mf][nf][j] + bv;
            }
        }
    }
}

// ---------------- bf16 propagation ----------------
// State rows are 64 bf16 = 32 u32 words = 128B. Wave = 1 node; half-waves
// (32 lanes) process alternating edges; lane owns features {2*l32, 2*l32+1}.
// Accumulate fp32, inject 0.1*h from fp32 h, cross-half combine via shfl_xor(32).

__global__ __launch_bounds__(256) void propb_kernel(const uint* __restrict__ xin,
                                                    const float* __restrict__ h,
                                                    const float* __restrict__ dinv,
                                                    const int* __restrict__ offs,
                                                    const int2* __restrict__ edat,
                                                    uint* __restrict__ xout, int N) {
    int node = blockIdx.x * 4 + (threadIdx.x >> 6);
    int lane = threadIdx.x & 63;
    if (node >= N) return;
    const int l32 = lane & 31;
    const int hi  = lane >> 5;
    int e0 = offs[node], e1 = offs[node + 1];

    float ax[4] = {0.f, 0.f, 0.f, 0.f};
    float ay[4] = {0.f, 0.f, 0.f, 0.f};
    int e = e0;
    for (; e + 8 <= e1; e += 8) {
#pragma unroll
        for (int i = 0; i < 4; ++i) {
            int2 ed = edat[e + 2 * i + hi];
            uint g = xin[(size_t)ed.x * 32 + l32];
            float w = __int_as_float(ed.y);
            ax[i] = fmaf(w, b2f_lo(g), ax[i]);
            ay[i] = fmaf(w, b2f_hi(g), ay[i]);
        }
    }
    for (; e + 2 <= e1; e += 2) {
        int2 ed = edat[e + hi];
        uint g = xin[(size_t)ed.x * 32 + l32];
        float w = __int_as_float(ed.y);
        ax[0] = fmaf(w, b2f_lo(g), ax[0]);
        ay[0] = fmaf(w, b2f_hi(g), ay[0]);
    }
    if (e < e1 && hi == 0) {   // odd leftover edge: half 0 only
        int2 ed = edat[e];
        uint g = xin[(size_t)ed.x * 32 + l32];
        float w = __int_as_float(ed.y);
        ax[1] = fmaf(w, b2f_lo(g), ax[1]);
        ay[1] = fmaf(w, b2f_hi(g), ay[1]);
    }
    float sx = (ax[0] + ax[1]) + (ax[2] + ax[3]);
    float sy = (ay[0] + ay[1]) + (ay[2] + ay[3]);
    sx += __shfl_xor(sx, 32);
    sy += __shfl_xor(sy, 32);
    // self-loop (after combine: added once)
    float di = dinv[node];
    uint gs = xin[(size_t)node * 32 + l32];
    sx = fmaf(di * di, b2f_lo(gs), sx);
    sy = fmaf(di * di, b2f_hi(gs), sy);
    float2 hv = *reinterpret_cast<const float2*>(&h[(size_t)node * 64 + l32 * 2]);
    float r0 = 0.9f * sx + 0.1f * hv.x;
    float r1 = 0.9f * sy + 0.1f * hv.y;
    if (hi == 0) xout[(size_t)node * 32 + l32] = packbf(r0, r1);
}

// final propagation fused with log-softmax (fp32 output)

__global__ __launch_bounds__(256) void propb_lsm_kernel(const uint* __restrict__ xin,
                                                        const float* __restrict__ h,
                                                        const float* __restrict__ dinv,
                                                        const int* __restrict__ offs,
                                                        const int2* __restrict__ edat,
                                                        float* __restrict__ out, int N) {
    int node = blockIdx.x * 4 + (threadIdx.x >> 6);
    int lane = threadIdx.x & 63;
    if (node >= N) return;
    const int l32 = lane & 31;
    const int hi  = lane >> 5;
    int e0 = offs[node], e1 = offs[node + 1];

    float ax[4] = {0.f, 0.f, 0.f, 0.f};
    float ay[4] = {0.f, 0.f, 0.f, 0.f};
    int e = e0;
    for (; e + 8 <= e1; e += 8) {
#pragma unroll
        for (int i = 0; i < 4; ++i) {
            int2 ed = edat[e + 2 * i + hi];
            uint g = xin[(size_t)ed.x * 32 + l32];
            float w = __int_as_float(ed.y);
            ax[i] = fmaf(w, b2f_lo(g), ax[i]);
            ay[i] = fmaf(w, b2f_hi(g), ay[i]);
        }
    }
    for (; e + 2 <= e1; e += 2) {
        int2 ed = edat[e + hi];
        uint g = xin[(size_t)ed.x * 32 + l32];
        float w = __int_as_float(ed.y);
        ax[0] = fmaf(w, b2f_lo(g), ax[0]);
        ay[0] = fmaf(w, b2f_hi(g), ay[0]);
    }
    if (e < e1 && hi == 0) {
        int2 ed = edat[e];
        uint g = xin[(size_t)ed.x * 32 + l32];
        float w = __int_as_float(ed.y);
        ax[1] = fmaf(w, b2f_lo(g), ax[1]);
        ay[1] = fmaf(w, b2f_hi(g), ay[1]);
    }
    float sx = (ax[0] + ax[1]) + (ax[2] + ax[3]);
    float sy = (ay[0] + ay[1]) + (ay[2] + ay[3]);
    sx += __shfl_xor(sx, 32);
    sy += __shfl_xor(sy, 32);
    float di = dinv[node];
    uint gs = xin[(size_t)node * 32 + l32];
    sx = fmaf(di * di, b2f_lo(gs), sx);
    sy = fmaf(di * di, b2f_hi(gs), sy);
    float2 hv = *reinterpret_cast<const float2*>(&h[(size_t)node * 64 + l32 * 2]);
    float r0 = 0.9f * sx + 0.1f * hv.x;
    float r1 = 0.9f * sy + 0.1f * hv.y;

    // log-softmax over the 64 features (2/lane x 32 lanes; halves hold copies)
    float m = fmaxf(r0, r1);
    for (int o = 16; o > 0; o >>= 1) m = fmaxf(m, __shfl_xor(m, o));
    float sum = expf(r0 - m) + expf(r1 - m);
    for (int o = 16; o > 0; o >>= 1) sum += __shfl_xor(sum, o);
    float ls = logf(sum);
    if (hi == 0) {
        float2 o2 = make_float2(r0 - m - ls, r1 - m - ls);
        *reinterpret_cast<float2*>(&out[(size_t)node * 64 + l32 * 2]) = o2;
    }
}

// ---------------- launch ----------------

static inline size_t align256(size_t x) { return (x + 255) & ~(size_t)255; }

extern "C" void kernel_launch(void* const* d_in, const int* in_sizes, int n_in,
                              void* d_out, int out_size, void* d_ws, size_t ws_size,
                              hipStream_t stream) {
    const float* x  = (const float*)d_in[0];
    const float* W1 = (const float*)d_in[1];
    const float* b1 = (const float*)d_in[2];
    const float* W2 = (const float*)d_in[3];
    const float* b2 = (const float*)d_in[4];
    const int*   ei = (const int*)d_in[5];

    const int N = in_sizes[0] / IN_DIM;
    const int E = in_sizes[5] / 2;
    const int nb = (N + 255) / 256;

    char* base = (char*)d_ws;
    size_t off = 0;
    ushort* xb  = (ushort*)(base + off); off += align256((size_t)N * IN_DIM * 2);        // 51.2MB
    ushort* w1b = (ushort*)(base + off); off += align256((size_t)HID_DIM * IN_DIM * 2);  // 256KB
    ushort* h1  = (ushort*)(base + off); off += align256((size_t)N * HID_DIM * 2);       // 25.6MB
    float* h    = (float*)(base + off);  off += align256((size_t)N * OUT_DIM * 4);       // 12.8MB
    float* dinv = (float*)(base + off);  off += align256((size_t)N * 4);
    int*   deg  = (int*)(base + off);    off += align256((size_t)N * 4);
    int*   offs = (int*)(base + off);    off += align256((size_t)(N + 1) * 4);
    int*   cur  = (int*)(base + off);    off += align256((size_t)N * 4);
    int*   bsum = (int*)(base + off);    off += align256((size_t)nb * 4);
    int2*  edat = (int2*)(base + off);   off += align256((size_t)E * 8);                  // 6.4MB

    // bf16 state buffers in the (freed-after-gemm1) xb region: 3 x 6.4MB
    uint* hb  = (uint*)xb;
    uint* xsa = hb  + (size_t)N * 32;
    uint* xsb = xsa + (size_t)N * 32;

    // ---- CSR build ----
    hipMemsetAsync(deg, 0, (size_t)N * 4, stream);
    hipMemsetAsync(cur, 0, (size_t)N * 4, stream);
    hist_kernel<<<(E + 255) / 256, 256, 0, stream>>>(ei, deg, E);
    scanA_kernel<<<nb, 256, 0, stream>>>(deg, offs, bsum, N);
    scanB_kernel<<<1, 256, 0, stream>>>(bsum, nb);
    scanC_kernel<<<nb, 256, 0, stream>>>(deg, bsum, offs, dinv, N, E);
    fill_kernel<<<(E + 255) / 256, 256, 0, stream>>>(ei, offs, cur, dinv, edat, E);

    // ---- bf16 conversion of inputs ----
    f2b_kernel<<<2048, 256, 0, stream>>>(x, xb, N * IN_DIM / 8);
    f2b_kernel<<<64, 256, 0, stream>>>(W1, w1b, HID_DIM * IN_DIM / 8);

    // ---- MLP (bf16 MFMA) ----
    {
        dim3 g(HID_DIM / 128, (N + 127) / 128);
        gemm1_mfma<<<g, 256, 0, stream>>>(xb, w1b, b1, h1, N);
    }
    {
        dim3 g((N + 127) / 128);
        gemm2_bf16<<<g, 256, 0, stream>>>(h1, W2, b2, h, N);
    }

    // ---- h -> bf16 (prop state seed) ----
    f2b_kernel<<<2048, 256, 0, stream>>>(h, (ushort*)hb, N * OUT_DIM / 8);

    // ---- K propagation steps (bf16 state; last fused w/ log-softmax) ----
    int blocks = (N + 3) / 4;
    propb_kernel<<<blocks, 256, 0, stream>>>(hb,  h, dinv, offs, edat, xsa, N);  // 1
    propb_kernel<<<blocks, 256, 0, stream>>>(xsa, h, dinv, offs, edat, xsb, N);  // 2
    propb_kernel<<<blocks, 256, 0, stream>>>(xsb, h, dinv, offs, edat, xsa, N);  // 3
    propb_kernel<<<blocks, 256, 0, stream>>>(xsa, h, dinv, offs, edat, xsb, N);  // 4
    propb_lsm_kernel<<<blocks, 256, 0, stream>>>(xsb, h, dinv, offs, edat,
                                                 (float*)d_out, N);              // 5 + lsm
}

// Round 6
// 281.893 us; speedup vs baseline: 2.9635x; 1.1685x over previous
//
#include <hip/hip_runtime.h>
#include <hip/hip_bf16.h>

#define IN_DIM  512
#define HID_DIM 256
#define OUT_DIM 64

typedef __attribute__((ext_vector_type(8))) short bf16x8;
typedef __attribute__((ext_vector_type(4))) float f32x4;

static __device__ __forceinline__ ushort f2b(float f) {
    __hip_bfloat16 b = __float2bfloat16(f);
    return *reinterpret_cast<ushort*>(&b);
}
static __device__ __forceinline__ float b2f_lo(uint u) {
    union { uint u; float f; } t; t.u = u << 16; return t.f;
}
static __device__ __forceinline__ float b2f_hi(uint u) {
    union { uint u; float f; } t; t.u = u & 0xFFFF0000u; return t.f;
}
static __device__ __forceinline__ uint packbf(float x, float y) {
    return (uint)f2b(x) | ((uint)f2b(y) << 16);
}

#define GLOAD16(g, l) __builtin_amdgcn_global_load_lds(                      \
    (const __attribute__((address_space(1))) void*)(g),                      \
    (__attribute__((address_space(3))) void*)(l), 16, 0, 0)

// ---------------- fp32 -> bf16 bulk convert (W1 only) ----------------

__global__ __launch_bounds__(256) void f2b_kernel(const float* __restrict__ in,
                                                  ushort* __restrict__ out, int n8) {
    for (int i = blockIdx.x * 256 + threadIdx.x; i < n8; i += gridDim.x * 256) {
        float4 a = *reinterpret_cast<const float4*>(&in[(size_t)i * 8]);
        float4 b = *reinterpret_cast<const float4*>(&in[(size_t)i * 8 + 4]);
        ushort4 lo = make_ushort4(f2b(a.x), f2b(a.y), f2b(a.z), f2b(a.w));
        ushort4 hi = make_ushort4(f2b(b.x), f2b(b.y), f2b(b.z), f2b(b.w));
        *reinterpret_cast<ushort4*>(&out[(size_t)i * 8])     = lo;
        *reinterpret_cast<ushort4*>(&out[(size_t)i * 8 + 4]) = hi;
    }
}

// ---------------- CSR build ----------------

__global__ void hist_kernel(const int* __restrict__ ei, int* __restrict__ deg, int E) {
    int e = blockIdx.x * 256 + threadIdx.x;
    if (e < E) atomicAdd(&deg[ei[E + e]], 1);
}

__global__ __launch_bounds__(256) void scanA_kernel(const int* __restrict__ deg,
                                                    int* __restrict__ offs,
                                                    int* __restrict__ bsum, int N) {
    __shared__ int sh[256];
    int tid = threadIdx.x;
    int i = blockIdx.x * 256 + tid;
    int v = (i < N) ? deg[i] : 0;
    sh[tid] = v;
    __syncthreads();
#pragma unroll
    for (int off = 1; off < 256; off <<= 1) {
        int t = (tid >= off) ? sh[tid - off] : 0;
        __syncthreads();
        sh[tid] += t;
        __syncthreads();
    }
    if (i < N) offs[i] = sh[tid] - v;
    if (tid == 255) bsum[blockIdx.x] = sh[255];
}

__global__ __launch_bounds__(256) void scanB_kernel(int* __restrict__ bsum, int nb) {
    __shared__ int sh[256];
    int tid = threadIdx.x;
    int v = (tid < nb) ? bsum[tid] : 0;
    sh[tid] = v;
    __syncthreads();
#pragma unroll
    for (int off = 1; off < 256; off <<= 1) {
        int t = (tid >= off) ? sh[tid - off] : 0;
        __syncthreads();
        sh[tid] += t;
        __syncthreads();
    }
    if (tid < nb) bsum[tid] = sh[tid] - v;
}

__global__ __launch_bounds__(256) void scanC_kernel(const int* __restrict__ deg,
                                                    const int* __restrict__ bsum,
                                                    int* __restrict__ offs,
                                                    float* __restrict__ dinv,
                                                    int N, int E) {
    int i = blockIdx.x * 256 + threadIdx.x;
    if (i < N) {
        offs[i] += bsum[i >> 8];
        dinv[i] = rsqrtf((float)(deg[i] + 1));
    }
    if (i == 0) offs[N] = E;
}

// edat[pos] = src(u16) | f2b(w)<<16  -- 4B per edge
__global__ void fill_kernel(const int* __restrict__ ei, const int* __restrict__ offs,
                            int* __restrict__ cursor, const float* __restrict__ dinv,
                            uint* __restrict__ edat, int E) {
    int e = blockIdx.x * 256 + threadIdx.x;
    if (e < E) {
        int s = ei[e];
        int d = ei[E + e];
        int pos = offs[d] + atomicAdd(&cursor[d], 1);
        edat[pos] = (uint)s | ((uint)f2b(dinv[d] * dinv[s]) << 16);
    }
}

// ---------------- GEMM1: h1[M,256] = bf16(relu(x[M,512] @ W1b[256,512]^T + b1)) ----
// A is read as fp32 directly (conversion fused into fragment read).
// global_load_lds(16B) staging for both; XOR-swizzled LDS; BK=64; 4 waves.

__global__ __launch_bounds__(256) void gemm1_f32a(const float* __restrict__ A,
                                                  const ushort* __restrict__ B,
                                                  const float* __restrict__ bias,
                                                  ushort* __restrict__ C, int M) {
    constexpr int K = IN_DIM;       // 512
    constexpr int NK = K / 64;      // 8 K-steps
    __shared__ float  Asf[128 * 64];   // 32KB fp32 A-tile
    __shared__ ushort Bs[128 * 64];    // 16KB bf16 B-tile

    const int tid  = threadIdx.x;
    const int lane = tid & 63;
    const int wid  = tid >> 6;
    const int wm = wid >> 1, wn = wid & 1;
    const int m0 = blockIdx.y * 128;
    const int n0 = blockIdx.x * 128;
    const int l15 = lane & 15;
    const int lq  = lane >> 4;

    // A staging: instr covers 4 rows x 16 16B-slots; swizzle at 32B-pair level.
    const int a_r   = lane >> 4;          // row within instr 0..3
    const int a_s16 = lane & 15;          // 16B slot 0..15
    const int a_pair = a_s16 >> 1, a_sub = a_s16 & 1;
    // B staging: instr covers 8 rows x 8 16B-slots; swizzle at 16B level.
    const int srow  = lane >> 3;
    const int sslot = (lane & 7) ^ srow;

    f32x4 acc[4][4];
#pragma unroll
    for (int i = 0; i < 4; ++i)
#pragma unroll
        for (int j = 0; j < 4; ++j) acc[i][j] = (f32x4)0.0f;

    for (int ks = 0; ks < NK; ++ks) {
        const int k0 = ks * 64;
        // B: 4 instrs/wave
#pragma unroll
        for (int q = 0; q < 4; ++q) {
            const int rbase = (wid * 4 + q) * 8;
            const int row = rbase + srow;
            const ushort* gb = B + (size_t)(n0 + row) * K + k0 + sslot * 8;
            GLOAD16(gb, &Bs[rbase * 64]);
        }
        // A: 8 instrs/wave (fp32)
#pragma unroll
        for (int q = 0; q < 8; ++q) {
            const int rbase = (wid * 8 + q) * 4;
            const int row = rbase + a_r;
            int am = m0 + row; if (am >= M) am = M - 1;
            const int col = k0 + ((a_pair ^ (row & 7)) << 3) + (a_sub << 2);
            const float* ga = A + (size_t)am * K + col;
            GLOAD16(ga, &Asf[rbase * 64]);
        }
        __syncthreads();
#pragma unroll
        for (int kk = 0; kk < 2; ++kk) {
            const int p = kk * 4 + lq;    // 32B pair slot = 8 elements
            bf16x8 af[4], bf[4];
#pragma unroll
            for (int f = 0; f < 4; ++f) {
                const int ar = wm * 64 + f * 16 + l15;
                const int fi = ar * 64 + ((p ^ (ar & 7)) << 3);
                f32x4 v0 = *reinterpret_cast<const f32x4*>(&Asf[fi]);
                f32x4 v1 = *reinterpret_cast<const f32x4*>(&Asf[fi + 4]);
                bf16x8 a;
                a[0] = (short)f2b(v0[0]); a[1] = (short)f2b(v0[1]);
                a[2] = (short)f2b(v0[2]); a[3] = (short)f2b(v0[3]);
                a[4] = (short)f2b(v1[0]); a[5] = (short)f2b(v1[1]);
                a[6] = (short)f2b(v1[2]); a[7] = (short)f2b(v1[3]);
                af[f] = a;
                const int br = wn * 64 + f * 16 + l15;
                bf[f] = *reinterpret_cast<const bf16x8*>(&Bs[br * 64 + ((p ^ (br & 7)) << 3)]);
            }
#pragma unroll
            for (int i = 0; i < 4; ++i)
#pragma unroll
                for (int j = 0; j < 4; ++j)
                    acc[i][j] = __builtin_amdgcn_mfma_f32_16x16x32_bf16(af[i], bf[j], acc[i][j], 0, 0, 0);
        }
        __syncthreads();
    }

    const int lr = lq * 4;
#pragma unroll
    for (int nf = 0; nf < 4; ++nf) {
        int col = n0 + wn * 64 + nf * 16 + l15;
        float bv = bias[col];
#pragma unroll
        for (int mf = 0; mf < 4; ++mf) {
#pragma unroll
            for (int j = 0; j < 4; ++j) {
                int row = m0 + wm * 64 + mf * 16 + lr + j;
                if (row < M) {
                    float v = fmaxf(acc[mf][nf][j] + bv, 0.f);
                    C[(size_t)row * HID_DIM + col] = f2b(v);
                }
            }
        }
    }
}

// ---------------- GEMM2: hb[M,64] = bf16(h1_bf16[M,256] @ W2[64,256]^T + b2) ----

#define LDT 40

__global__ __launch_bounds__(256) void gemm2_bf16(const ushort* __restrict__ A,
                                                  const float* __restrict__ B,
                                                  const float* __restrict__ bias,
                                                  ushort* __restrict__ Cb,
                                                  int M) {
    constexpr int K = HID_DIM;
    constexpr int NK = K / 32;
    __shared__ ushort As[128 * LDT];
    __shared__ ushort Bs[64 * LDT];

    const int tid = threadIdx.x;
    const int lane = tid & 63;
    const int wid = tid >> 6;
    const int wm = wid >> 1, wn = wid & 1;
    const int m0 = blockIdx.x * 128;
    const int l15 = lane & 15;
    const int koff = (lane >> 4) * 8;

    f32x4 acc[4][2];
#pragma unroll
    for (int i = 0; i < 4; ++i)
#pragma unroll
        for (int j = 0; j < 2; ++j) acc[i][j] = (f32x4)0.0f;

    uint4 rawA[2];
    float4 rbv[2];
#pragma unroll
    for (int i = 0; i < 2; ++i) {
        int slot = tid + i * 256;
        int rowA = slot >> 2, c8 = (slot & 3) << 3;
        int m = m0 + rowA;
        rawA[i] = (m < M) ? *reinterpret_cast<const uint4*>(&A[(size_t)m * K + c8])
                          : make_uint4(0u, 0u, 0u, 0u);
        int rowB = slot >> 3, c4 = (slot & 7) << 2;
        rbv[i] = *reinterpret_cast<const float4*>(&B[(size_t)rowB * K + c4]);
    }
#pragma unroll
    for (int i = 0; i < 2; ++i) {
        int slot = tid + i * 256;
        int rowA = slot >> 2, c8 = (slot & 3) << 3;
        *reinterpret_cast<uint4*>(&As[rowA * LDT + c8]) = rawA[i];
        int rowB = slot >> 3, c4 = (slot & 7) << 2;
        ushort4 ub = make_ushort4(f2b(rbv[i].x), f2b(rbv[i].y), f2b(rbv[i].z), f2b(rbv[i].w));
        *reinterpret_cast<ushort4*>(&Bs[rowB * LDT + c4]) = ub;
    }
    __syncthreads();

    for (int ks = 0; ks < NK; ++ks) {
        if (ks + 1 < NK) {
            int k0 = (ks + 1) * 32;
#pragma unroll
            for (int i = 0; i < 2; ++i) {
                int slot = tid + i * 256;
                int rowA = slot >> 2, c8 = (slot & 3) << 3;
                int m = m0 + rowA;
                rawA[i] = (m < M) ? *reinterpret_cast<const uint4*>(&A[(size_t)m * K + k0 + c8])
                                  : make_uint4(0u, 0u, 0u, 0u);
                int rowB = slot >> 3, c4 = (slot & 7) << 2;
                rbv[i] = *reinterpret_cast<const float4*>(&B[(size_t)rowB * K + k0 + c4]);
            }
        }
        bf16x8 af[4], bf[2];
#pragma unroll
        for (int f = 0; f < 4; ++f)
            af[f] = *reinterpret_cast<const bf16x8*>(&As[(wm * 64 + f * 16 + l15) * LDT + koff]);
#pragma unroll
        for (int f = 0; f < 2; ++f)
            bf[f] = *reinterpret_cast<const bf16x8*>(&Bs[(wn * 32 + f * 16 + l15) * LDT + koff]);
#pragma unroll
        for (int i = 0; i < 4; ++i)
#pragma unroll
            for (int j = 0; j < 2; ++j)
                acc[i][j] = __builtin_amdgcn_mfma_f32_16x16x32_bf16(af[i], bf[j], acc[i][j], 0, 0, 0);
        __syncthreads();
        if (ks + 1 < NK) {
#pragma unroll
            for (int i = 0; i < 2; ++i) {
                int slot = tid + i * 256;
                int rowA = slot >> 2, c8 = (slot & 3) << 3;
                *reinterpret_cast<uint4*>(&As[rowA * LDT + c8]) = rawA[i];
                int rowB = slot >> 3, c4 = (slot & 7) << 2;
                ushort4 ub = make_ushort4(f2b(rbv[i].x), f2b(rbv[i].y), f2b(rbv[i].z), f2b(rbv[i].w));
                *reinterpret_cast<ushort4*>(&Bs[rowB * LDT + c4]) = ub;
            }
            __syncthreads();
        }
    }

    const int lr = (lane >> 4) * 4;
#pragma unroll
    for (int nf = 0; nf < 2; ++nf) {
        int col = wn * 32 + nf * 16 + l15;
        float bv = bias[col];
#pragma unroll
        for (int mf = 0; mf < 4; ++mf) {
#pragma unroll
            for (int j = 0; j < 4; ++j) {
                int row = m0 + wm * 64 + mf * 16 + lr + j;
                if (row < M)
                    Cb[(size_t)row * OUT_DIM + col] = f2b(acc[mf][nf][j] + bv);
            }
        }
    }
}

// ---------------- bf16 propagation: wave = 2 independent nodes (1/half) -------
// Lane owns features {2*l32, 2*l32+1}. Accumulate fp32; anchor 0.1*hb (bf16).

__global__ __launch_bounds__(256) void propb_kernel(const uint* __restrict__ xin,
                                                    const uint* __restrict__ hb,
                                                    const float* __restrict__ dinv,
                                                    const int* __restrict__ offs,
                                                    const uint* __restrict__ edat,
                                                    uint* __restrict__ xout, int N) {
    int node = blockIdx.x * 8 + (threadIdx.x >> 5);
    int l32 = threadIdx.x & 31;
    if (node >= N) return;
    int e0 = offs[node], e1 = offs[node + 1];

    float ax[4] = {0.f, 0.f, 0.f, 0.f};
    float ay[4] = {0.f, 0.f, 0.f, 0.f};
    int e = e0;
    for (; e + 8 <= e1; e += 8) {
        uint p0 = edat[e+0], p1 = edat[e+1], p2 = edat[e+2], p3 = edat[e+3];
        uint p4 = edat[e+4], p5 = edat[e+5], p6 = edat[e+6], p7 = edat[e+7];
        uint g0 = xin[(size_t)(p0 & 0xFFFFu) * 32 + l32];
        uint g1 = xin[(size_t)(p1 & 0xFFFFu) * 32 + l32];
        uint g2 = xin[(size_t)(p2 & 0xFFFFu) * 32 + l32];
        uint g3 = xin[(size_t)(p3 & 0xFFFFu) * 32 + l32];
        uint g4 = xin[(size_t)(p4 & 0xFFFFu) * 32 + l32];
        uint g5 = xin[(size_t)(p5 & 0xFFFFu) * 32 + l32];
        uint g6 = xin[(size_t)(p6 & 0xFFFFu) * 32 + l32];
        uint g7 = xin[(size_t)(p7 & 0xFFFFu) * 32 + l32];
        ax[0] = fmaf(b2f_hi(p0), b2f_lo(g0), ax[0]); ay[0] = fmaf(b2f_hi(p0), b2f_hi(g0), ay[0]);
        ax[1] = fmaf(b2f_hi(p1), b2f_lo(g1), ax[1]); ay[1] = fmaf(b2f_hi(p1), b2f_hi(g1), ay[1]);
        ax[2] = fmaf(b2f_hi(p2), b2f_lo(g2), ax[2]); ay[2] = fmaf(b2f_hi(p2), b2f_hi(g2), ay[2]);
        ax[3] = fmaf(b2f_hi(p3), b2f_lo(g3), ax[3]); ay[3] = fmaf(b2f_hi(p3), b2f_hi(g3), ay[3]);
        ax[0] = fmaf(b2f_hi(p4), b2f_lo(g4), ax[0]); ay[0] = fmaf(b2f_hi(p4), b2f_hi(g4), ay[0]);
        ax[1] = fmaf(b2f_hi(p5), b2f_lo(g5), ax[1]); ay[1] = fmaf(b2f_hi(p5), b2f_hi(g5), ay[1]);
        ax[2] = fmaf(b2f_hi(p6), b2f_lo(g6), ax[2]); ay[2] = fmaf(b2f_hi(p6), b2f_hi(g6), ay[2]);
        ax[3] = fmaf(b2f_hi(p7), b2f_lo(g7), ax[3]); ay[3] = fmaf(b2f_hi(p7), b2f_hi(g7), ay[3]);
    }
    for (; e < e1; ++e) {
        uint p = edat[e];
        uint g = xin[(size_t)(p & 0xFFFFu) * 32 + l32];
        ax[0] = fmaf(b2f_hi(p), b2f_lo(g), ax[0]);
        ay[0] = fmaf(b2f_hi(p), b2f_hi(g), ay[0]);
    }
    float sx = (ax[0] + ax[1]) + (ax[2] + ax[3]);
    float sy = (ay[0] + ay[1]) + (ay[2] + ay[3]);
    float di = dinv[node];
    uint gs = xin[(size_t)node * 32 + l32];
    sx = fmaf(di * di, b2f_lo(gs), sx);
    sy = fmaf(di * di, b2f_hi(gs), sy);
    uint ah = hb[(size_t)node * 32 + l32];
    float r0 = 0.9f * sx + 0.1f * b2f_lo(ah);
    float r1 = 0.9f * sy + 0.1f * b2f_hi(ah);
    xout[(size_t)node * 32 + l32] = packbf(r0, r1);
}

// final propagation fused with log-softmax (fp32 output)

__global__ __launch_bounds__(256) void propb_lsm_kernel(const uint* __restrict__ xin,
                                                        const uint* __restrict__ hb,
                                                        const float* __restrict__ dinv,
                                                        const int* __restrict__ offs,
                                                        const uint* __restrict__ edat,
                                                        float* __restrict__ out, int N) {
    int node = blockIdx.x * 8 + (threadIdx.x >> 5);
    int l32 = threadIdx.x & 31;
    if (node >= N) return;
    int e0 = offs[node], e1 = offs[node + 1];

    float ax[4] = {0.f, 0.f, 0.f, 0.f};
    float ay[4] = {0.f, 0.f, 0.f, 0.f};
    int e = e0;
    for (; e + 8 <= e1; e += 8) {
        uint p0 = edat[e+0], p1 = edat[e+1], p2 = edat[e+2], p3 = edat[e+3];
        uint p4 = edat[e+4], p5 = edat[e+5], p6 = edat[e+6], p7 = edat[e+7];
        uint g0 = xin[(size_t)(p0 & 0xFFFFu) * 32 + l32];
        uint g1 = xin[(size_t)(p1 & 0xFFFFu) * 32 + l32];
        uint g2 = xin[(size_t)(p2 & 0xFFFFu) * 32 + l32];
        uint g3 = xin[(size_t)(p3 & 0xFFFFu) * 32 + l32];
        uint g4 = xin[(size_t)(p4 & 0xFFFFu) * 32 + l32];
        uint g5 = xin[(size_t)(p5 & 0xFFFFu) * 32 + l32];
        uint g6 = xin[(size_t)(p6 & 0xFFFFu) * 32 + l32];
        uint g7 = xin[(size_t)(p7 & 0xFFFFu) * 32 + l32];
        ax[0] = fmaf(b2f_hi(p0), b2f_lo(g0), ax[0]); ay[0] = fmaf(b2f_hi(p0), b2f_hi(g0), ay[0]);
        ax[1] = fmaf(b2f_hi(p1), b2f_lo(g1), ax[1]); ay[1] = fmaf(b2f_hi(p1), b2f_hi(g1), ay[1]);
        ax[2] = fmaf(b2f_hi(p2), b2f_lo(g2), ax[2]); ay[2] = fmaf(b2f_hi(p2), b2f_hi(g2), ay[2]);
        ax[3] = fmaf(b2f_hi(p3), b2f_lo(g3), ax[3]); ay[3] = fmaf(b2f_hi(p3), b2f_hi(g3), ay[3]);
        ax[0] = fmaf(b2f_hi(p4), b2f_lo(g4), ax[0]); ay[0] = fmaf(b2f_hi(p4), b2f_hi(g4), ay[0]);
        ax[1] = fmaf(b2f_hi(p5), b2f_lo(g5), ax[1]); ay[1] = fmaf(b2f_hi(p5), b2f_hi(g5), ay[1]);
        ax[2] = fmaf(b2f_hi(p6), b2f_lo(g6), ax[2]); ay[2] = fmaf(b2f_hi(p6), b2f_hi(g6), ay[2]);
        ax[3] = fmaf(b2f_hi(p7), b2f_lo(g7), ax[3]); ay[3] = fmaf(b2f_hi(p7), b2f_hi(g7), ay[3]);
    }
    for (; e < e1; ++e) {
        uint p = edat[e];
        uint g = xin[(size_t)(p & 0xFFFFu) * 32 + l32];
        ax[0] = fmaf(b2f_hi(p), b2f_lo(g), ax[0]);
        ay[0] = fmaf(b2f_hi(p), b2f_hi(g), ay[0]);
    }
    float sx = (ax[0] + ax[1]) + (ax[2] + ax[3]);
    float sy = (ay[0] + ay[1]) + (ay[2] + ay[3]);
    float di = dinv[node];
    uint gs = xin[(size_t)node * 32 + l32];
    sx = fmaf(di * di, b2f_lo(gs), sx);
    sy = fmaf(di * di, b2f_hi(gs), sy);
    uint ah = hb[(size_t)node * 32 + l32];
    float r0 = 0.9f * sx + 0.1f * b2f_lo(ah);
    float r1 = 0.9f * sy + 0.1f * b2f_hi(ah);

    // log-softmax over 64 features within the 32-lane half (2 per lane)
    float m = fmaxf(r0, r1);
    for (int o = 16; o > 0; o >>= 1) m = fmaxf(m, __shfl_xor(m, o));
    float sum = expf(r0 - m) + expf(r1 - m);
    for (int o = 16; o > 0; o >>= 1) sum += __shfl_xor(sum, o);
    float ls = logf(sum);
    float2 o2 = make_float2(r0 - m - ls, r1 - m - ls);
    *reinterpret_cast<float2*>(&out[(size_t)node * 64 + l32 * 2]) = o2;
}

// ---------------- launch ----------------

static inline size_t align256(size_t x) { return (x + 255) & ~(size_t)255; }

extern "C" void kernel_launch(void* const* d_in, const int* in_sizes, int n_in,
                              void* d_out, int out_size, void* d_ws, size_t ws_size,
                              hipStream_t stream) {
    const float* x  = (const float*)d_in[0];
    const float* W1 = (const float*)d_in[1];
    const float* b1 = (const float*)d_in[2];
    const float* W2 = (const float*)d_in[3];
    const float* b2 = (const float*)d_in[4];
    const int*   ei = (const int*)d_in[5];

    const int N = in_sizes[0] / IN_DIM;
    const int E = in_sizes[5] / 2;
    const int nb = (N + 255) / 256;

    char* base = (char*)d_ws;
    size_t off = 0;
    uint*  hb  = (uint*)(base + off);    off += align256((size_t)N * 32 * 4);            // 6.4MB
    uint*  xsa = (uint*)(base + off);    off += align256((size_t)N * 32 * 4);            // 6.4MB
    uint*  xsb = (uint*)(base + off);    off += align256((size_t)N * 32 * 4);            // 6.4MB
    ushort* w1b = (ushort*)(base + off); off += align256((size_t)HID_DIM * IN_DIM * 2);  // 256KB
    ushort* h1  = (ushort*)(base + off); off += align256((size_t)N * HID_DIM * 2);       // 25.6MB
    float* dinv = (float*)(base + off);  off += align256((size_t)N * 4);
    int*   deg  = (int*)(base + off);    off += align256((size_t)N * 4);
    int*   offs = (int*)(base + off);    off += align256((size_t)(N + 1) * 4);
    int*   cur  = (int*)(base + off);    off += align256((size_t)N * 4);
    int*   bsum = (int*)(base + off);    off += align256((size_t)nb * 4);
    uint*  edat = (uint*)(base + off);   off += align256((size_t)E * 4);                  // 3.2MB

    // ---- CSR build ----
    hipMemsetAsync(deg, 0, (size_t)N * 4, stream);
    hipMemsetAsync(cur, 0, (size_t)N * 4, stream);
    hist_kernel<<<(E + 255) / 256, 256, 0, stream>>>(ei, deg, E);
    scanA_kernel<<<nb, 256, 0, stream>>>(deg, offs, bsum, N);
    scanB_kernel<<<1, 256, 0, stream>>>(bsum, nb);
    scanC_kernel<<<nb, 256, 0, stream>>>(deg, bsum, offs, dinv, N, E);
    fill_kernel<<<(E + 255) / 256, 256, 0, stream>>>(ei, offs, cur, dinv, edat, E);

    // ---- W1 -> bf16 (x is consumed fp32 directly by gemm1) ----
    f2b_kernel<<<64, 256, 0, stream>>>(W1, w1b, HID_DIM * IN_DIM / 8);

    // ---- MLP (bf16 MFMA) ----
    {
        dim3 g(HID_DIM / 128, (N + 127) / 128);
        gemm1_f32a<<<g, 256, 0, stream>>>(x, w1b, b1, h1, N);
    }
    {
        dim3 g((N + 127) / 128);
        gemm2_bf16<<<g, 256, 0, stream>>>(h1, W2, b2, (ushort*)hb, N);
    }

    // ---- K propagation steps (bf16 state; last fused w/ log-softmax) ----
    int blocks = (N + 7) / 8;
    propb_kernel<<<blocks, 256, 0, stream>>>(hb,  hb, dinv, offs, edat, xsa, N);  // 1
    propb_kernel<<<blocks, 256, 0, stream>>>(xsa, hb, dinv, offs, edat, xsb, N);  // 2
    propb_kernel<<<blocks, 256, 0, stream>>>(xsb, hb, dinv, offs, edat, xsa, N);  // 3
    propb_kernel<<<blocks, 256, 0, stream>>>(xsa, hb, dinv, offs, edat, xsb, N);  // 4
    propb_lsm_kernel<<<blocks, 256, 0, stream>>>(xsb, hb, dinv, offs, edat,
                                                 (float*)d_out, N);               // 5 + lsm
}